// Round 4
// baseline (213.047 us; speedup 1.0000x reference)
//
#include <hip/hip_runtime.h>

#define B_  8
#define N_  1024
#define D_  768
#define H_  12
#define HD_ 64
#define M_  (B_ * N_)            // 8192
#define WELEM (D_ * D_)          // 589824
#define XELEM ((size_t)M_ * D_)  // 6291456

typedef _Float16 f16;
typedef f16   f16x8  __attribute__((ext_vector_type(8)));
typedef short bf16x8 __attribute__((ext_vector_type(8)));
typedef float f32x4  __attribute__((ext_vector_type(4)));
typedef unsigned short u16;

__device__ __forceinline__ u16 f2bf(float f) {
    unsigned int x = __float_as_uint(f);
    return (u16)((x + 0x7fffu + ((x >> 16) & 1u)) >> 16);   // RNE
}
__device__ __forceinline__ u16 f2h(float f) {
    return __builtin_bit_cast(u16, (f16)f);                 // RNE
}
// packed f32x2 -> bf16x2 in one VALU op
__device__ __forceinline__ unsigned int cvtpk_bf16(float lo, float hi) {
    unsigned int r;
    asm("v_cvt_pk_bf16_f32 %0, %1, %2" : "=v"(r) : "v"(lo), "v"(hi));
    return r;
}
#if __has_builtin(__builtin_amdgcn_exp2f)
#define EXP2F(x) __builtin_amdgcn_exp2f(x)
#else
#define EXP2F(x) exp2f(x)
#endif

#define LOG2E_   1.4426950408889634f
#define EXPBIAS_ 28.853900817779268f   // 20 * log2(e)

// direct global->LDS DMA, 16B per lane; dst = wave-uniform base + lane*16
typedef __attribute__((address_space(3))) unsigned int       as3_u32;
typedef __attribute__((address_space(1))) const unsigned int as1_u32;
__device__ __forceinline__ void dma16(const void* g, void* l) {
    __builtin_amdgcn_global_load_lds((as1_u32*)g, (as3_u32*)l, 16, 0, 0);
}

// ---------------------------------------------------------------------------
// x (fp32, M x D) -> f16, same layout.
// ---------------------------------------------------------------------------
__global__ __launch_bounds__(256) void cvt_x(const float* __restrict__ X,
                                             u16* __restrict__ Xh) {
    int idx = blockIdx.x * 256 + threadIdx.x;
    float4 v = ((const float4*)X)[idx];
    ushort4 o = {f2h(v.x), f2h(v.y), f2h(v.z), f2h(v.w)};
    ((ushort4*)Xh)[idx] = o;
}

// ---------------------------------------------------------------------------
// W (fp32, [k][n]) -> Wt (f16, [n][k]) for all 4 weights. 64x64 tiles.
// ---------------------------------------------------------------------------
__global__ __launch_bounds__(256) void cvt_w(
    const float* __restrict__ w0, const float* __restrict__ w1,
    const float* __restrict__ w2, const float* __restrict__ w3,
    u16* __restrict__ Wt) {
    const float* W = blockIdx.y == 0 ? w0 : blockIdx.y == 1 ? w1
                   : blockIdx.y == 2 ? w2 : w3;
    u16* dst = Wt + (size_t)blockIdx.y * WELEM;
    const int t  = threadIdx.x;
    const int tk = (blockIdx.x % 12) * 64, tn = (blockIdx.x / 12) * 64;
    __shared__ __align__(16) float tile[64][68];
#pragma unroll
    for (int i = 0; i < 4; ++i) {
        int r = (t >> 4) + i * 16, c4 = (t & 15) * 4;
        float4 v = *(const float4*)(W + (size_t)(tk + r) * D_ + tn + c4);
        *(float4*)&tile[r][c4] = v;
    }
    __syncthreads();
#pragma unroll
    for (int i = 0; i < 4; ++i) {
        int nr = (t >> 4) + i * 16, kc = (t & 15) * 4;
        ushort4 o = {f2h(tile[kc + 0][nr]), f2h(tile[kc + 1][nr]),
                     f2h(tile[kc + 2][nr]), f2h(tile[kc + 3][nr])};
        *(ushort4*)(dst + (size_t)(tn + nr) * D_ + tk + kc) = o;
    }
}

// ---------------------------------------------------------------------------
// QKV projection, MFMA 16x16x32 f16, 128x64 tile, BK=64, DOUBLE-BUFFERED
// v2-style: issue kk+1 loads FIRST, then counted vmcnt(6) (waits only kk's
// 6 loads; the new 6 stay in flight across both barriers), barrier, compute,
// barrier. LDS 48 KB -> 3 blocks/CU. Full (z,n,m) XCD swizzle.
// Q output pre-scaled by log2(e).
// ---------------------------------------------------------------------------
__global__ __launch_bounds__(256) void gemm_qkv(
    const u16* __restrict__ Xh, const u16* __restrict__ Wt,
    const float* __restrict__ bq, const float* __restrict__ bk,
    const float* __restrict__ bv, u16* __restrict__ Qf,
    u16* __restrict__ Kf, u16* __restrict__ Vt) {
    __shared__ __align__(16) u16 As[2][128 * 64];   // 2 x 16 KB
    __shared__ __align__(16) u16 Bs[2][64 * 64];    // 2 x 8 KB

    const int id  = blockIdx.x;                  // 2304
    const int xcd = id & 7, idx = id >> 3;       // 288 per XCD
    const int m0  = (xcd * 8 + idx / 36) * 128;
    const int rem = idx % 36;
    const int z   = rem / 12, n0 = (rem % 12) * 64;

    const u16* Wz = Wt + (size_t)z * WELEM;
    const float* bias = z == 0 ? bq : z == 1 ? bk : bv;

    const int t = threadIdx.x, lane = t & 63, w = t >> 6;
    const int wm = w >> 1, wn = w & 1;
    const int quad = lane >> 4, ln = lane & 15;
    const int drow = lane >> 3, dcl = (lane & 7) ^ ((lane >> 3) & 7);

    // prologue: stage K-step 0 into buffer 0
#pragma unroll
    for (int j = 0; j < 4; ++j) {
        int i = w * 4 + j, row = i * 8 + drow;
        dma16(Xh + (size_t)(m0 + row) * D_ + dcl * 8, &As[0][i * 512]);
    }
#pragma unroll
    for (int j = 0; j < 2; ++j) {
        int i = w * 2 + j, row = i * 8 + drow;
        dma16(Wz + (size_t)(n0 + row) * D_ + dcl * 8, &Bs[0][i * 512]);
    }

    f32x4 acc[4][2] = {};
#pragma unroll 2
    for (int kk = 0; kk < 12; ++kk) {
        const int cur = kk & 1;
        // issue kk+1 loads into buf^1 (its last readers were at kk-1, behind
        // the trailing barrier), then wait only for kk's 6 loads.
        if (kk < 11) {
            const int k1 = (kk + 1) * 64;
#pragma unroll
            for (int j = 0; j < 4; ++j) {
                int i = w * 4 + j, row = i * 8 + drow;
                dma16(Xh + (size_t)(m0 + row) * D_ + k1 + dcl * 8,
                      &As[cur ^ 1][i * 512]);
            }
#pragma unroll
            for (int j = 0; j < 2; ++j) {
                int i = w * 2 + j, row = i * 8 + drow;
                dma16(Wz + (size_t)(n0 + row) * D_ + k1 + dcl * 8,
                      &Bs[cur ^ 1][i * 512]);
            }
            asm volatile("s_waitcnt vmcnt(6)" ::: "memory");
        } else {
            asm volatile("s_waitcnt vmcnt(0)" ::: "memory");
        }
        __builtin_amdgcn_s_barrier();
        __builtin_amdgcn_sched_barrier(0);

        f16x8 a[4][2], b[2][2];
#pragma unroll
        for (int mt = 0; mt < 4; ++mt)
#pragma unroll
            for (int ks = 0; ks < 2; ++ks)
                a[mt][ks] = *(const f16x8*)&As[cur][(wm * 64 + mt * 16 + ln) * 64 +
                                                    (((ks * 4 + quad) ^ (ln & 7)) * 8)];
#pragma unroll
        for (int nt = 0; nt < 2; ++nt)
#pragma unroll
            for (int ks = 0; ks < 2; ++ks)
                b[nt][ks] = *(const f16x8*)&Bs[cur][(wn * 32 + nt * 16 + ln) * 64 +
                                                    (((ks * 4 + quad) ^ (ln & 7)) * 8)];
#pragma unroll
        for (int mt = 0; mt < 4; ++mt)
#pragma unroll
            for (int nt = 0; nt < 2; ++nt) {
                acc[mt][nt] = __builtin_amdgcn_mfma_f32_16x16x32_f16(
                    a[mt][0], b[nt][0], acc[mt][nt], 0, 0, 0);
                acc[mt][nt] = __builtin_amdgcn_mfma_f32_16x16x32_f16(
                    a[mt][1], b[nt][1], acc[mt][nt], 0, 0, 0);
            }
        __builtin_amdgcn_sched_barrier(0);
        __builtin_amdgcn_s_barrier();   // all waves done reading buf[cur]
    }
    const int h = n0 >> 6;
#pragma unroll
    for (int nt = 0; nt < 2; ++nt) {
        int hd = wn * 32 + nt * 16 + ln;
        float bv_ = bias[n0 + hd];
#pragma unroll
        for (int mt = 0; mt < 4; ++mt) {
            int mb = m0 + wm * 64 + mt * 16 + quad * 4;
            int bb = mb >> 10, ns = mb & 1023;
            if (z == 0) {
#pragma unroll
                for (int r = 0; r < 4; ++r)
                    Qf[(((size_t)bb * H_ + h) * N_ + ns + r) * HD_ + hd] =
                        f2h((acc[mt][nt][r] + bv_) * LOG2E_);
            } else if (z == 1) {
#pragma unroll
                for (int r = 0; r < 4; ++r)
                    Kf[(((size_t)bb * H_ + h) * N_ + ns + r) * HD_ + hd] =
                        f2h(acc[mt][nt][r] + bv_);
            } else {
                ushort4 o = {f2bf(acc[mt][nt][0] + bv_), f2bf(acc[mt][nt][1] + bv_),
                             f2bf(acc[mt][nt][2] + bv_), f2bf(acc[mt][nt][3] + bv_)};
                *(ushort4*)(Vt + (((size_t)bb * H_ + h) * HD_ + hd) * N_ + ns) = o;
            }
        }
    }
}

// ---------------------------------------------------------------------------
// Flash attention, MFMA. 128-q blocks, permuted-K staging, packed P writes.
// v2 (R1-proven, 51.6 us): double-buffered K/V with prefetch-before-wait
// (counted vmcnt(4), raw s_barrier x2 -- never vmcnt(0) in steady state),
// native exp2 (Q pre-scaled by log2e), v_cvt_pk_bf16_f32 P packing,
// setprio around MFMA clusters. LDS 50 KB; grid = 768 = 3 blocks/CU.
// ---------------------------------------------------------------------------
__global__ __launch_bounds__(256) void attn_mfma(
    const u16* __restrict__ Qg, const u16* __restrict__ Kg,
    const u16* __restrict__ Vtg, u16* __restrict__ Og) {
    __shared__ __align__(16) u16 Ks[2][64 * 64];  // f16, rows permuted by g(rho)
    __shared__ __align__(16) u16 Vs[2][64 * 64];  // bf16 [hd][key], swizzled
    __shared__ __align__(16) u16 Ps[128 * 72];    // bf16 [q][key], wave-private rows

    const int t = threadIdx.x, lane = t & 63, w = t >> 6;
    const int quad = lane >> 4, ln = lane & 15;
    const int drow = lane >> 3, dcl = (lane & 7) ^ ((lane >> 3) & 7);
    const int id  = blockIdx.x;                  // 768
    const int id2 = (id & 7) * 96 + (id >> 3);
    const int bh  = id2 >> 3, qt = id2 & 7;
    const u16* Qh  = Qg  + ((size_t)bh * N_ + qt * 128) * HD_;
    const u16* Kh  = Kg  + (size_t)bh * N_ * HD_;
    const u16* Vth = Vtg + (size_t)bh * HD_ * N_;
    u16*       Oh  = Og  + ((size_t)bh * N_ + qt * 128) * HD_;

    const int rho0 = (w * 2 + 0) * 8 + drow;
    const int rho1 = (w * 2 + 1) * 8 + drow;
    const int gk0  = 4 * (rho0 & 15) + (rho0 >> 4);
    const int gk1  = 4 * (rho1 & 15) + (rho1 >> 4);

    f16x8 aq[2][2];
#pragma unroll
    for (int mt = 0; mt < 2; ++mt)
#pragma unroll
        for (int ks = 0; ks < 2; ++ks)
            aq[mt][ks] = *(const f16x8*)(Qh + (size_t)(w * 32 + mt * 16 + ln) * HD_ +
                                         ks * 32 + quad * 8);

    float lsum[2][4] = {};
    f32x4 oacc[2][4] = {};

    // prologue: stage kt=0 into buffer 0
    dma16(Kh + (size_t)gk0 * HD_ + dcl * 8, &Ks[0][(w * 2 + 0) * 512]);
    dma16(Kh + (size_t)gk1 * HD_ + dcl * 8, &Ks[0][(w * 2 + 1) * 512]);
    dma16(Vth + (size_t)rho0 * N_ + dcl * 8, &Vs[0][(w * 2 + 0) * 512]);
    dma16(Vth + (size_t)rho1 * N_ + dcl * 8, &Vs[0][(w * 2 + 1) * 512]);

#pragma unroll 2
    for (int kt = 0; kt < 16; ++kt) {
        const int cur = kt & 1;
        // issue next tile's loads into the other buffer (last read at kt-1,
        // one full barrier behind -> safe), then wait only for the CURRENT
        // buffer's 4 loads: 4 newer stay in flight across the barrier.
        if (kt < 15) {
            const int nk = (kt + 1) * 64;
            dma16(Kh + (size_t)(nk + gk0) * HD_ + dcl * 8, &Ks[cur ^ 1][(w * 2 + 0) * 512]);
            dma16(Kh + (size_t)(nk + gk1) * HD_ + dcl * 8, &Ks[cur ^ 1][(w * 2 + 1) * 512]);
            dma16(Vth + (size_t)rho0 * N_ + nk + dcl * 8, &Vs[cur ^ 1][(w * 2 + 0) * 512]);
            dma16(Vth + (size_t)rho1 * N_ + nk + dcl * 8, &Vs[cur ^ 1][(w * 2 + 1) * 512]);
            asm volatile("s_waitcnt vmcnt(4)" ::: "memory");
        } else {
            asm volatile("s_waitcnt vmcnt(0)" ::: "memory");
        }
        __builtin_amdgcn_s_barrier();
        __builtin_amdgcn_sched_barrier(0);

        // S = Q K^T; D col ln of sub-tile nt = global key 4*ln+nt
        f32x4 sf[2][4];
        __builtin_amdgcn_s_setprio(1);
#pragma unroll
        for (int nt = 0; nt < 4; ++nt) {
            f16x8 b0 = *(const f16x8*)&Ks[cur][(nt * 16 + ln) * 64 + ((quad) ^ (ln & 7)) * 8];
            f16x8 b1 = *(const f16x8*)&Ks[cur][(nt * 16 + ln) * 64 + ((4 + quad) ^ (ln & 7)) * 8];
#pragma unroll
            for (int mt = 0; mt < 2; ++mt) {
                f32x4 zz = {};
                sf[mt][nt] = __builtin_amdgcn_mfma_f32_16x16x32_f16(aq[mt][0], b0, zz, 0, 0, 0);
                sf[mt][nt] = __builtin_amdgcn_mfma_f32_16x16x32_f16(aq[mt][1], b1, sf[mt][nt], 0, 0, 0);
            }
        }
        __builtin_amdgcn_s_setprio(0);

        // p = exp2(s' - 20*log2e)  (Q pre-scaled by log2e);
        // pack 4 contiguous keys -> one b64 LDS write via v_cvt_pk_bf16_f32
#pragma unroll
        for (int mt = 0; mt < 2; ++mt)
#pragma unroll
            for (int r = 0; r < 4; ++r) {
                float e0 = EXP2F(sf[mt][0][r] - EXPBIAS_);
                float e1 = EXP2F(sf[mt][1][r] - EXPBIAS_);
                float e2 = EXP2F(sf[mt][2][r] - EXPBIAS_);
                float e3 = EXP2F(sf[mt][3][r] - EXPBIAS_);
                uint2 pk;
                pk.x = cvtpk_bf16(e0, e1);
                pk.y = cvtpk_bf16(e2, e3);
                int q = w * 32 + mt * 16 + quad * 4 + r;
                *(uint2*)&Ps[q * 72 + ln * 4] = pk;
                // sum the ROUNDED values so denominator matches P exactly
                lsum[mt][r] += __uint_as_float(pk.x << 16) +
                               __uint_as_float(pk.x & 0xffff0000u) +
                               __uint_as_float(pk.y << 16) +
                               __uint_as_float(pk.y & 0xffff0000u);
            }

        // O += P V
        __builtin_amdgcn_s_setprio(1);
#pragma unroll
        for (int mt = 0; mt < 2; ++mt) {
            bf16x8 ap0 = *(const bf16x8*)&Ps[(w * 32 + mt * 16 + ln) * 72 + quad * 8];
            bf16x8 ap1 = *(const bf16x8*)&Ps[(w * 32 + mt * 16 + ln) * 72 + 32 + quad * 8];
#pragma unroll
            for (int nt = 0; nt < 4; ++nt) {
                bf16x8 bv0 = *(const bf16x8*)&Vs[cur][(nt * 16 + ln) * 64 +
                                                      ((quad ^ (ln & 7)) * 8)];
                oacc[mt][nt] = __builtin_amdgcn_mfma_f32_16x16x32_bf16(
                    ap0, bv0, oacc[mt][nt], 0, 0, 0);
                bf16x8 bv1 = *(const bf16x8*)&Vs[cur][(nt * 16 + ln) * 64 +
                                                      (((4 + quad) ^ (ln & 7)) * 8)];
                oacc[mt][nt] = __builtin_amdgcn_mfma_f32_16x16x32_bf16(
                    ap1, bv1, oacc[mt][nt], 0, 0, 0);
            }
        }
        __builtin_amdgcn_s_setprio(0);
        __builtin_amdgcn_sched_barrier(0);
        __builtin_amdgcn_s_barrier();   // all waves done reading buf[cur]
    }

    const float sc = 0.036084391824351615f;  // 1/sqrt(768), AFTER softmax
#pragma unroll
    for (int mt = 0; mt < 2; ++mt)
#pragma unroll
        for (int r = 0; r < 4; ++r) {
            float l = lsum[mt][r];
            l += __shfl_xor(l, 1);
            l += __shfl_xor(l, 2);
            l += __shfl_xor(l, 4);
            l += __shfl_xor(l, 8);
            float inv = sc / l;
#pragma unroll
            for (int nt = 0; nt < 4; ++nt)
                Oh[(size_t)(w * 32 + mt * 16 + quad * 4 + r) * HD_ + nt * 16 + ln] =
                    f2h(oacc[mt][nt][r] * inv);
        }
}

// ---------------------------------------------------------------------------
// Output projection: out = O @ Wo + bo. 128x64, DOUBLE-BUFFERED v2-style
// (prefetch-before, counted vmcnt(6), 2 barriers) + XCD swizzle.
// 768 = 3 blocks/CU.
// ---------------------------------------------------------------------------
__global__ __launch_bounds__(256) void gemm_out(
    const u16* __restrict__ Ob, const u16* __restrict__ Wto,
    const float* __restrict__ bias, float* __restrict__ Out) {
    __shared__ __align__(16) u16 As[2][128 * 64];
    __shared__ __align__(16) u16 Bs[2][64 * 64];

    const int id  = blockIdx.x;                  // 768
    const int id2 = (id & 7) * 96 + (id >> 3);
    const int m0  = (id2 / 12) * 128, n0 = (id2 % 12) * 64;

    const int t = threadIdx.x, lane = t & 63, w = t >> 6;
    const int wm = w >> 1, wn = w & 1;
    const int quad = lane >> 4, ln = lane & 15;
    const int drow = lane >> 3, dcl = (lane & 7) ^ ((lane >> 3) & 7);

    // prologue: stage K-step 0 (head 0) into buffer 0
#pragma unroll
    for (int j = 0; j < 4; ++j) {
        int i = w * 4 + j, row = i * 8 + drow;
        int m = m0 + row, bb = m >> 10, ns = m & 1023;
        dma16(Ob + (((size_t)bb * H_ + 0) * N_ + ns) * HD_ + dcl * 8, &As[0][i * 512]);
    }
#pragma unroll
    for (int j = 0; j < 2; ++j) {
        int i = w * 2 + j, row = i * 8 + drow;
        dma16(Wto + (size_t)(n0 + row) * D_ + dcl * 8, &Bs[0][i * 512]);
    }

    f32x4 acc[4][2] = {};
#pragma unroll 2
    for (int kk = 0; kk < 12; ++kk) {
        const int cur = kk & 1;
        if (kk < 11) {
            const int head = kk + 1, k1 = head * 64;
#pragma unroll
            for (int j = 0; j < 4; ++j) {
                int i = w * 4 + j, row = i * 8 + drow;
                int m = m0 + row, bb = m >> 10, ns = m & 1023;
                dma16(Ob + (((size_t)bb * H_ + head) * N_ + ns) * HD_ + dcl * 8,
                      &As[cur ^ 1][i * 512]);
            }
#pragma unroll
            for (int j = 0; j < 2; ++j) {
                int i = w * 2 + j, row = i * 8 + drow;
                dma16(Wto + (size_t)(n0 + row) * D_ + k1 + dcl * 8,
                      &Bs[cur ^ 1][i * 512]);
            }
            asm volatile("s_waitcnt vmcnt(6)" ::: "memory");
        } else {
            asm volatile("s_waitcnt vmcnt(0)" ::: "memory");
        }
        __builtin_amdgcn_s_barrier();
        __builtin_amdgcn_sched_barrier(0);

        f16x8 a[4][2], b[2][2];
#pragma unroll
        for (int mt = 0; mt < 4; ++mt)
#pragma unroll
            for (int ks = 0; ks < 2; ++ks)
                a[mt][ks] = *(const f16x8*)&As[cur][(wm * 64 + mt * 16 + ln) * 64 +
                                                    (((ks * 4 + quad) ^ (ln & 7)) * 8)];
#pragma unroll
        for (int nt = 0; nt < 2; ++nt)
#pragma unroll
            for (int ks = 0; ks < 2; ++ks)
                b[nt][ks] = *(const f16x8*)&Bs[cur][(wn * 32 + nt * 16 + ln) * 64 +
                                                    (((ks * 4 + quad) ^ (ln & 7)) * 8)];
#pragma unroll
        for (int mt = 0; mt < 4; ++mt)
#pragma unroll
            for (int nt = 0; nt < 2; ++nt) {
                acc[mt][nt] = __builtin_amdgcn_mfma_f32_16x16x32_f16(
                    a[mt][0], b[nt][0], acc[mt][nt], 0, 0, 0);
                acc[mt][nt] = __builtin_amdgcn_mfma_f32_16x16x32_f16(
                    a[mt][1], b[nt][1], acc[mt][nt], 0, 0, 0);
            }
        __builtin_amdgcn_sched_barrier(0);
        __builtin_amdgcn_s_barrier();   // all waves done reading buf[cur]
    }
#pragma unroll
    for (int nt = 0; nt < 2; ++nt) {
        int n = n0 + wn * 32 + nt * 16 + ln;
        float bv_ = bias[n];
#pragma unroll
        for (int mt = 0; mt < 4; ++mt) {
            int mb = m0 + wm * 64 + mt * 16 + quad * 4;
#pragma unroll
            for (int r = 0; r < 4; ++r)
                Out[(size_t)(mb + r) * D_ + n] = acc[mt][nt][r] + bv_;
        }
    }
}

extern "C" void kernel_launch(void* const* d_in, const int* in_sizes, int n_in,
                              void* d_out, int out_size, void* d_ws, size_t ws_size,
                              hipStream_t stream) {
    const float* x  = (const float*)d_in[0];
    const float* Wq = (const float*)d_in[1];
    const float* bq = (const float*)d_in[2];
    const float* Wk = (const float*)d_in[3];
    const float* bk = (const float*)d_in[4];
    const float* Wv = (const float*)d_in[5];
    const float* bv = (const float*)d_in[6];
    const float* Wo = (const float*)d_in[7];
    const float* bo = (const float*)d_in[8];

    u16* Xh = (u16*)d_ws;                  // x f16, 12.6 MB
    u16* Wt = Xh + XELEM;                  // 4 W^T f16
    u16* Qf = Wt + 4 * (size_t)WELEM;      // Q f16 (B,H,N,HD), pre-scaled by log2e
    u16* Kf = Qf + XELEM;                  // K f16 (B,H,N,HD)
    u16* Vt = Kf + XELEM;                  // V bf16 (B,H,HD,N)
    u16* Ob = Vt + XELEM;                  // attn out f16 (B,H,N,HD)

    cvt_x<<<dim3((int)(XELEM / 4 / 256)), 256, 0, stream>>>(x, Xh);
    cvt_w<<<dim3(144, 4), 256, 0, stream>>>(Wq, Wk, Wv, Wo, Wt);
    gemm_qkv<<<dim3(2304), 256, 0, stream>>>(Xh, Wt, bq, bk, bv, Qf, Kf, Vt);
    attn_mfma<<<dim3(768), 256, 0, stream>>>(Qf, Kf, Vt, Ob);
    gemm_out<<<dim3(768), 256, 0, stream>>>(
        Ob, Wt + 3 * (size_t)WELEM, bo, (float*)d_out);
}

// Round 5
// 188.686 us; speedup vs baseline: 1.1291x; 1.1291x over previous
//
#include <hip/hip_runtime.h>

#define B_  8
#define N_  1024
#define D_  768
#define H_  12
#define HD_ 64
#define M_  (B_ * N_)            // 8192
#define WELEM (D_ * D_)          // 589824
#define XELEM ((size_t)M_ * D_)  // 6291456

typedef _Float16 f16;
typedef f16   f16x8  __attribute__((ext_vector_type(8)));
typedef short bf16x8 __attribute__((ext_vector_type(8)));
typedef float f32x4  __attribute__((ext_vector_type(4)));
typedef unsigned short u16;

__device__ __forceinline__ u16 f2bf(float f) {
    unsigned int x = __float_as_uint(f);
    return (u16)((x + 0x7fffu + ((x >> 16) & 1u)) >> 16);   // RNE
}
__device__ __forceinline__ u16 f2h(float f) {
    return __builtin_bit_cast(u16, (f16)f);                 // RNE
}
// packed f32x2 -> bf16x2 in one VALU op
__device__ __forceinline__ unsigned int cvtpk_bf16(float lo, float hi) {
    unsigned int r;
    asm("v_cvt_pk_bf16_f32 %0, %1, %2" : "=v"(r) : "v"(lo), "v"(hi));
    return r;
}
#if __has_builtin(__builtin_amdgcn_exp2f)
#define EXP2F(x) __builtin_amdgcn_exp2f(x)
#else
#define EXP2F(x) exp2f(x)
#endif

#define LOG2E_   1.4426950408889634f
#define EXPBIAS_ 28.853900817779268f   // 20 * log2(e)

// direct global->LDS DMA, 16B per lane; dst = wave-uniform base + lane*16
typedef __attribute__((address_space(3))) unsigned int       as3_u32;
typedef __attribute__((address_space(1))) const unsigned int as1_u32;
__device__ __forceinline__ void dma16(const void* g, void* l) {
    __builtin_amdgcn_global_load_lds((as1_u32*)g, (as3_u32*)l, 16, 0, 0);
}

// ---------------------------------------------------------------------------
// x (fp32, M x D) -> f16, same layout.
// ---------------------------------------------------------------------------
__global__ __launch_bounds__(256) void cvt_x(const float* __restrict__ X,
                                             u16* __restrict__ Xh) {
    int idx = blockIdx.x * 256 + threadIdx.x;
    float4 v = ((const float4*)X)[idx];
    ushort4 o = {f2h(v.x), f2h(v.y), f2h(v.z), f2h(v.w)};
    ((ushort4*)Xh)[idx] = o;
}

// ---------------------------------------------------------------------------
// W (fp32, [k][n]) -> Wt (f16, [n][k]) for all 4 weights. 64x64 tiles.
// ---------------------------------------------------------------------------
__global__ __launch_bounds__(256) void cvt_w(
    const float* __restrict__ w0, const float* __restrict__ w1,
    const float* __restrict__ w2, const float* __restrict__ w3,
    u16* __restrict__ Wt) {
    const float* W = blockIdx.y == 0 ? w0 : blockIdx.y == 1 ? w1
                   : blockIdx.y == 2 ? w2 : w3;
    u16* dst = Wt + (size_t)blockIdx.y * WELEM;
    const int t  = threadIdx.x;
    const int tk = (blockIdx.x % 12) * 64, tn = (blockIdx.x / 12) * 64;
    __shared__ __align__(16) float tile[64][68];
#pragma unroll
    for (int i = 0; i < 4; ++i) {
        int r = (t >> 4) + i * 16, c4 = (t & 15) * 4;
        float4 v = *(const float4*)(W + (size_t)(tk + r) * D_ + tn + c4);
        *(float4*)&tile[r][c4] = v;
    }
    __syncthreads();
#pragma unroll
    for (int i = 0; i < 4; ++i) {
        int nr = (t >> 4) + i * 16, kc = (t & 15) * 4;
        ushort4 o = {f2h(tile[kc + 0][nr]), f2h(tile[kc + 1][nr]),
                     f2h(tile[kc + 2][nr]), f2h(tile[kc + 3][nr])};
        *(ushort4*)(dst + (size_t)(tn + nr) * D_ + tk + kc) = o;
    }
}

// ---------------------------------------------------------------------------
// QKV projection, MFMA 16x16x32 f16, 128x64 tile, BK=64, single-buffer
// (R1-proven, <=51.5 us) with full (z,n,m) XCD swizzle.
// Q output pre-scaled by log2(e).
// ---------------------------------------------------------------------------
__global__ __launch_bounds__(256) void gemm_qkv(
    const u16* __restrict__ Xh, const u16* __restrict__ Wt,
    const float* __restrict__ bq, const float* __restrict__ bk,
    const float* __restrict__ bv, u16* __restrict__ Qf,
    u16* __restrict__ Kf, u16* __restrict__ Vt) {
    __shared__ __align__(16) u16 As[128 * 64];   // 16 KB
    __shared__ __align__(16) u16 Bs[64 * 64];    // 8 KB

    const int id  = blockIdx.x;                  // 2304
    const int xcd = id & 7, idx = id >> 3;       // 288 per XCD
    const int m0  = (xcd * 8 + idx / 36) * 128;
    const int rem = idx % 36;
    const int z   = rem / 12, n0 = (rem % 12) * 64;

    const u16* Wz = Wt + (size_t)z * WELEM;
    const float* bias = z == 0 ? bq : z == 1 ? bk : bv;

    const int t = threadIdx.x, lane = t & 63, w = t >> 6;
    const int wm = w >> 1, wn = w & 1;
    const int quad = lane >> 4, ln = lane & 15;
    const int drow = lane >> 3, dcl = (lane & 7) ^ ((lane >> 3) & 7);

    f32x4 acc[4][2] = {};
    for (int k0 = 0; k0 < D_; k0 += 64) {
        __syncthreads();
#pragma unroll
        for (int j = 0; j < 4; ++j) {
            int i = w * 4 + j, row = i * 8 + drow;
            dma16(Xh + (size_t)(m0 + row) * D_ + k0 + dcl * 8, &As[i * 512]);
        }
#pragma unroll
        for (int j = 0; j < 2; ++j) {
            int i = w * 2 + j, row = i * 8 + drow;
            dma16(Wz + (size_t)(n0 + row) * D_ + k0 + dcl * 8, &Bs[i * 512]);
        }
        __syncthreads();
        f16x8 a[4][2], b[2][2];
#pragma unroll
        for (int mt = 0; mt < 4; ++mt)
#pragma unroll
            for (int ks = 0; ks < 2; ++ks)
                a[mt][ks] = *(const f16x8*)&As[(wm * 64 + mt * 16 + ln) * 64 +
                                               (((ks * 4 + quad) ^ (ln & 7)) * 8)];
#pragma unroll
        for (int nt = 0; nt < 2; ++nt)
#pragma unroll
            for (int ks = 0; ks < 2; ++ks)
                b[nt][ks] = *(const f16x8*)&Bs[(wn * 32 + nt * 16 + ln) * 64 +
                                               (((ks * 4 + quad) ^ (ln & 7)) * 8)];
#pragma unroll
        for (int mt = 0; mt < 4; ++mt)
#pragma unroll
            for (int nt = 0; nt < 2; ++nt) {
                acc[mt][nt] = __builtin_amdgcn_mfma_f32_16x16x32_f16(
                    a[mt][0], b[nt][0], acc[mt][nt], 0, 0, 0);
                acc[mt][nt] = __builtin_amdgcn_mfma_f32_16x16x32_f16(
                    a[mt][1], b[nt][1], acc[mt][nt], 0, 0, 0);
            }
    }
    const int h = n0 >> 6;
#pragma unroll
    for (int nt = 0; nt < 2; ++nt) {
        int hd = wn * 32 + nt * 16 + ln;
        float bv_ = bias[n0 + hd];
#pragma unroll
        for (int mt = 0; mt < 4; ++mt) {
            int mb = m0 + wm * 64 + mt * 16 + quad * 4;
            int bb = mb >> 10, ns = mb & 1023;
            if (z == 0) {
#pragma unroll
                for (int r = 0; r < 4; ++r)
                    Qf[(((size_t)bb * H_ + h) * N_ + ns + r) * HD_ + hd] =
                        f2h((acc[mt][nt][r] + bv_) * LOG2E_);
            } else if (z == 1) {
#pragma unroll
                for (int r = 0; r < 4; ++r)
                    Kf[(((size_t)bb * H_ + h) * N_ + ns + r) * HD_ + hd] =
                        f2h(acc[mt][nt][r] + bv_);
            } else {
                ushort4 o = {f2bf(acc[mt][nt][0] + bv_), f2bf(acc[mt][nt][1] + bv_),
                             f2bf(acc[mt][nt][2] + bv_), f2bf(acc[mt][nt][3] + bv_)};
                *(ushort4*)(Vt + (((size_t)bb * H_ + h) * HD_ + hd) * N_ + ns) = o;
            }
        }
    }
}

// ---------------------------------------------------------------------------
// Flash attention, MFMA. v4: 8 WAVES x 16 q-rows (512 threads), same
// QBLK=128 / KVBLK=64 / LDS 50 KB (3 blocks/CU -> 24 waves/CU, 6/SIMD:
// 2x the TLP of the 4-wave version to cover phase stalls). Pipeline is
// the proven v2: prefetch-before-wait, counted vmcnt(2), 2 barriers/kt.
// Per-wave state halves (aq 8, oacc 16, sf 16 VGPRs).
// ---------------------------------------------------------------------------
__global__ __launch_bounds__(512, 6) void attn_mfma(
    const u16* __restrict__ Qg, const u16* __restrict__ Kg,
    const u16* __restrict__ Vtg, u16* __restrict__ Og) {
    __shared__ __align__(16) u16 Ks[2][64 * 64];  // f16, rows permuted by g(rho)
    __shared__ __align__(16) u16 Vs[2][64 * 64];  // bf16 [hd][key], swizzled
    __shared__ __align__(16) u16 Ps[128 * 72];    // bf16 [q][key], wave-private rows

    const int t = threadIdx.x, lane = t & 63, w = t >> 6;   // w in 0..7
    const int quad = lane >> 4, ln = lane & 15;
    const int drow = lane >> 3, dcl = (lane & 7) ^ ((lane >> 3) & 7);
    const int id  = blockIdx.x;                  // 768
    const int id2 = (id & 7) * 96 + (id >> 3);
    const int bh  = id2 >> 3, qt = id2 & 7;
    const u16* Qh  = Qg  + ((size_t)bh * N_ + qt * 128) * HD_;
    const u16* Kh  = Kg  + (size_t)bh * N_ * HD_;
    const u16* Vth = Vtg + (size_t)bh * HD_ * N_;
    u16*       Oh  = Og  + ((size_t)bh * N_ + qt * 128) * HD_;

    const int rho = w * 8 + drow;                // 0..63: K-group / V-hd row
    const int gk  = 4 * (rho & 15) + (rho >> 4); // K row permutation

    f16x8 aq[2];
#pragma unroll
    for (int ks = 0; ks < 2; ++ks)
        aq[ks] = *(const f16x8*)(Qh + (size_t)(w * 16 + ln) * HD_ +
                                 ks * 32 + quad * 8);

    float lsum[4] = {};
    f32x4 oacc[4] = {};

    // prologue: stage kt=0 into buffer 0 (1 K-dma + 1 V-dma per wave)
    dma16(Kh + (size_t)gk * HD_ + dcl * 8, &Ks[0][w * 512]);
    dma16(Vth + (size_t)rho * N_ + dcl * 8, &Vs[0][w * 512]);

#pragma unroll 2
    for (int kt = 0; kt < 16; ++kt) {
        const int cur = kt & 1;
        // issue next tile's loads into the other buffer (last read at kt-1,
        // one full barrier behind -> safe), then wait only for the CURRENT
        // buffer's 2 loads: the 2 newer stay in flight across the barrier.
        if (kt < 15) {
            const int nk = (kt + 1) * 64;
            dma16(Kh + (size_t)(nk + gk) * HD_ + dcl * 8, &Ks[cur ^ 1][w * 512]);
            dma16(Vth + (size_t)rho * N_ + nk + dcl * 8, &Vs[cur ^ 1][w * 512]);
            asm volatile("s_waitcnt vmcnt(2)" ::: "memory");
        } else {
            asm volatile("s_waitcnt vmcnt(0)" ::: "memory");
        }
        __builtin_amdgcn_s_barrier();
        __builtin_amdgcn_sched_barrier(0);

        // S = Q K^T; D col ln of sub-tile nt = global key 4*ln+nt
        f32x4 sf[4];
        __builtin_amdgcn_s_setprio(1);
#pragma unroll
        for (int nt = 0; nt < 4; ++nt) {
            f16x8 b0 = *(const f16x8*)&Ks[cur][(nt * 16 + ln) * 64 + ((quad) ^ (ln & 7)) * 8];
            f16x8 b1 = *(const f16x8*)&Ks[cur][(nt * 16 + ln) * 64 + ((4 + quad) ^ (ln & 7)) * 8];
            f32x4 zz = {};
            sf[nt] = __builtin_amdgcn_mfma_f32_16x16x32_f16(aq[0], b0, zz, 0, 0, 0);
            sf[nt] = __builtin_amdgcn_mfma_f32_16x16x32_f16(aq[1], b1, sf[nt], 0, 0, 0);
        }
        __builtin_amdgcn_s_setprio(0);

        // p = exp2(s' - 20*log2e)  (Q pre-scaled by log2e);
        // pack 4 contiguous keys -> one b64 LDS write via v_cvt_pk_bf16_f32
#pragma unroll
        for (int r = 0; r < 4; ++r) {
            float e0 = EXP2F(sf[0][r] - EXPBIAS_);
            float e1 = EXP2F(sf[1][r] - EXPBIAS_);
            float e2 = EXP2F(sf[2][r] - EXPBIAS_);
            float e3 = EXP2F(sf[3][r] - EXPBIAS_);
            uint2 pk;
            pk.x = cvtpk_bf16(e0, e1);
            pk.y = cvtpk_bf16(e2, e3);
            int q = w * 16 + quad * 4 + r;
            *(uint2*)&Ps[q * 72 + ln * 4] = pk;
            // sum the ROUNDED values so denominator matches P exactly
            lsum[r] += __uint_as_float(pk.x << 16) +
                       __uint_as_float(pk.x & 0xffff0000u) +
                       __uint_as_float(pk.y << 16) +
                       __uint_as_float(pk.y & 0xffff0000u);
        }

        // O += P V
        __builtin_amdgcn_s_setprio(1);
        {
            bf16x8 ap0 = *(const bf16x8*)&Ps[(w * 16 + ln) * 72 + quad * 8];
            bf16x8 ap1 = *(const bf16x8*)&Ps[(w * 16 + ln) * 72 + 32 + quad * 8];
#pragma unroll
            for (int nt = 0; nt < 4; ++nt) {
                bf16x8 bv0 = *(const bf16x8*)&Vs[cur][(nt * 16 + ln) * 64 +
                                                      ((quad ^ (ln & 7)) * 8)];
                oacc[nt] = __builtin_amdgcn_mfma_f32_16x16x32_bf16(
                    ap0, bv0, oacc[nt], 0, 0, 0);
                bf16x8 bv1 = *(const bf16x8*)&Vs[cur][(nt * 16 + ln) * 64 +
                                                      (((4 + quad) ^ (ln & 7)) * 8)];
                oacc[nt] = __builtin_amdgcn_mfma_f32_16x16x32_bf16(
                    ap1, bv1, oacc[nt], 0, 0, 0);
            }
        }
        __builtin_amdgcn_s_setprio(0);
        __builtin_amdgcn_sched_barrier(0);
        __builtin_amdgcn_s_barrier();   // all waves done reading buf[cur]
    }

    const float sc = 0.036084391824351615f;  // 1/sqrt(768), AFTER softmax
#pragma unroll
    for (int r = 0; r < 4; ++r) {
        float l = lsum[r];
        l += __shfl_xor(l, 1);
        l += __shfl_xor(l, 2);
        l += __shfl_xor(l, 4);
        l += __shfl_xor(l, 8);
        float inv = sc / l;
#pragma unroll
        for (int nt = 0; nt < 4; ++nt)
            Oh[(size_t)(w * 16 + quad * 4 + r) * HD_ + nt * 16 + ln] =
                f2h(oacc[nt][r] * inv);
    }
}

// ---------------------------------------------------------------------------
// Output projection: out = O @ Wo + bo. 128x64 single-buffer (R1-proven)
// + XCD swizzle. 768 = 3 blocks/CU.
// ---------------------------------------------------------------------------
__global__ __launch_bounds__(256) void gemm_out(
    const u16* __restrict__ Ob, const u16* __restrict__ Wto,
    const float* __restrict__ bias, float* __restrict__ Out) {
    __shared__ __align__(16) u16 As[128 * 64];
    __shared__ __align__(16) u16 Bs[64 * 64];

    const int id  = blockIdx.x;                  // 768
    const int id2 = (id & 7) * 96 + (id >> 3);
    const int m0  = (id2 / 12) * 128, n0 = (id2 % 12) * 64;

    const int t = threadIdx.x, lane = t & 63, w = t >> 6;
    const int wm = w >> 1, wn = w & 1;
    const int quad = lane >> 4, ln = lane & 15;
    const int drow = lane >> 3, dcl = (lane & 7) ^ ((lane >> 3) & 7);

    f32x4 acc[4][2] = {};
    for (int k0 = 0; k0 < D_; k0 += 64) {
        int head = k0 >> 6;
        __syncthreads();
#pragma unroll
        for (int j = 0; j < 4; ++j) {
            int i = w * 4 + j, row = i * 8 + drow;
            int m = m0 + row, bb = m >> 10, ns = m & 1023;
            dma16(Ob + (((size_t)bb * H_ + head) * N_ + ns) * HD_ + dcl * 8, &As[i * 512]);
        }
#pragma unroll
        for (int j = 0; j < 2; ++j) {
            int i = w * 2 + j, row = i * 8 + drow;
            dma16(Wto + (size_t)(n0 + row) * D_ + k0 + dcl * 8, &Bs[i * 512]);
        }
        __syncthreads();
        f16x8 a[4][2], b[2][2];
#pragma unroll
        for (int mt = 0; mt < 4; ++mt)
#pragma unroll
            for (int ks = 0; ks < 2; ++ks)
                a[mt][ks] = *(const f16x8*)&As[(wm * 64 + mt * 16 + ln) * 64 +
                                               (((ks * 4 + quad) ^ (ln & 7)) * 8)];
#pragma unroll
        for (int nt = 0; nt < 2; ++nt)
#pragma unroll
            for (int ks = 0; ks < 2; ++ks)
                b[nt][ks] = *(const f16x8*)&Bs[(wn * 32 + nt * 16 + ln) * 64 +
                                               (((ks * 4 + quad) ^ (ln & 7)) * 8)];
#pragma unroll
        for (int mt = 0; mt < 4; ++mt)
#pragma unroll
            for (int nt = 0; nt < 2; ++nt) {
                acc[mt][nt] = __builtin_amdgcn_mfma_f32_16x16x32_f16(
                    a[mt][0], b[nt][0], acc[mt][nt], 0, 0, 0);
                acc[mt][nt] = __builtin_amdgcn_mfma_f32_16x16x32_f16(
                    a[mt][1], b[nt][1], acc[mt][nt], 0, 0, 0);
            }
    }
#pragma unroll
    for (int nt = 0; nt < 2; ++nt) {
        int n = n0 + wn * 32 + nt * 16 + ln;
        float bv_ = bias[n];
#pragma unroll
        for (int mt = 0; mt < 4; ++mt) {
            int mb = m0 + wm * 64 + mt * 16 + quad * 4;
#pragma unroll
            for (int r = 0; r < 4; ++r)
                Out[(size_t)(mb + r) * D_ + n] = acc[mt][nt][r] + bv_;
        }
    }
}

extern "C" void kernel_launch(void* const* d_in, const int* in_sizes, int n_in,
                              void* d_out, int out_size, void* d_ws, size_t ws_size,
                              hipStream_t stream) {
    const float* x  = (const float*)d_in[0];
    const float* Wq = (const float*)d_in[1];
    const float* bq = (const float*)d_in[2];
    const float* Wk = (const float*)d_in[3];
    const float* bk = (const float*)d_in[4];
    const float* Wv = (const float*)d_in[5];
    const float* bv = (const float*)d_in[6];
    const float* Wo = (const float*)d_in[7];
    const float* bo = (const float*)d_in[8];

    u16* Xh = (u16*)d_ws;                  // x f16, 12.6 MB
    u16* Wt = Xh + XELEM;                  // 4 W^T f16
    u16* Qf = Wt + 4 * (size_t)WELEM;      // Q f16 (B,H,N,HD), pre-scaled by log2e
    u16* Kf = Qf + XELEM;                  // K f16 (B,H,N,HD)
    u16* Vt = Kf + XELEM;                  // V bf16 (B,H,HD,N)
    u16* Ob = Vt + XELEM;                  // attn out f16 (B,H,N,HD)

    cvt_x<<<dim3((int)(XELEM / 4 / 256)), 256, 0, stream>>>(x, Xh);
    cvt_w<<<dim3(144, 4), 256, 0, stream>>>(Wq, Wk, Wv, Wo, Wt);
    gemm_qkv<<<dim3(2304), 256, 0, stream>>>(Xh, Wt, bq, bk, bv, Qf, Kf, Vt);
    attn_mfma<<<dim3(768), 512, 0, stream>>>(Qf, Kf, Vt, Ob);
    gemm_out<<<dim3(768), 256, 0, stream>>>(
        Ob, Wt + 3 * (size_t)WELEM, bo, (float*)d_out);
}

// Round 6
// 187.916 us; speedup vs baseline: 1.1337x; 1.0041x over previous
//
#include <hip/hip_runtime.h>

#define B_  8
#define N_  1024
#define D_  768
#define H_  12
#define HD_ 64
#define M_  (B_ * N_)            // 8192
#define WELEM (D_ * D_)          // 589824
#define XELEM ((size_t)M_ * D_)  // 6291456

typedef _Float16 f16;
typedef f16   f16x8  __attribute__((ext_vector_type(8)));
typedef short bf16x8 __attribute__((ext_vector_type(8)));
typedef float f32x4  __attribute__((ext_vector_type(4)));
typedef unsigned short u16;

__device__ __forceinline__ u16 f2bf(float f) {
    unsigned int x = __float_as_uint(f);
    return (u16)((x + 0x7fffu + ((x >> 16) & 1u)) >> 16);   // RNE
}
__device__ __forceinline__ u16 f2h(float f) {
    return __builtin_bit_cast(u16, (f16)f);                 // RNE
}
// packed f32x2 -> bf16x2 in one VALU op
__device__ __forceinline__ unsigned int cvtpk_bf16(float lo, float hi) {
    unsigned int r;
    asm("v_cvt_pk_bf16_f32 %0, %1, %2" : "=v"(r) : "v"(lo), "v"(hi));
    return r;
}
#if __has_builtin(__builtin_amdgcn_exp2f)
#define EXP2F(x) __builtin_amdgcn_exp2f(x)
#else
#define EXP2F(x) exp2f(x)
#endif

#define LOG2E_   1.4426950408889634f
#define EXPBIAS_ 28.853900817779268f   // 20 * log2(e)

// direct global->LDS DMA, 16B per lane; dst = wave-uniform base + lane*16
typedef __attribute__((address_space(3))) unsigned int       as3_u32;
typedef __attribute__((address_space(1))) const unsigned int as1_u32;
__device__ __forceinline__ void dma16(const void* g, void* l) {
    __builtin_amdgcn_global_load_lds((as1_u32*)g, (as3_u32*)l, 16, 0, 0);
}

// ---------------------------------------------------------------------------
// x (fp32, M x D) -> f16, same layout.
// ---------------------------------------------------------------------------
__global__ __launch_bounds__(256) void cvt_x(const float* __restrict__ X,
                                             u16* __restrict__ Xh) {
    int idx = blockIdx.x * 256 + threadIdx.x;
    float4 v = ((const float4*)X)[idx];
    ushort4 o = {f2h(v.x), f2h(v.y), f2h(v.z), f2h(v.w)};
    ((ushort4*)Xh)[idx] = o;
}

// ---------------------------------------------------------------------------
// W (fp32, [k][n]) -> Wt (f16, [n][k]) for all 4 weights. 64x64 tiles.
// ---------------------------------------------------------------------------
__global__ __launch_bounds__(256) void cvt_w(
    const float* __restrict__ w0, const float* __restrict__ w1,
    const float* __restrict__ w2, const float* __restrict__ w3,
    u16* __restrict__ Wt) {
    const float* W = blockIdx.y == 0 ? w0 : blockIdx.y == 1 ? w1
                   : blockIdx.y == 2 ? w2 : w3;
    u16* dst = Wt + (size_t)blockIdx.y * WELEM;
    const int t  = threadIdx.x;
    const int tk = (blockIdx.x % 12) * 64, tn = (blockIdx.x / 12) * 64;
    __shared__ __align__(16) float tile[64][68];
#pragma unroll
    for (int i = 0; i < 4; ++i) {
        int r = (t >> 4) + i * 16, c4 = (t & 15) * 4;
        float4 v = *(const float4*)(W + (size_t)(tk + r) * D_ + tn + c4);
        *(float4*)&tile[r][c4] = v;
    }
    __syncthreads();
#pragma unroll
    for (int i = 0; i < 4; ++i) {
        int nr = (t >> 4) + i * 16, kc = (t & 15) * 4;
        ushort4 o = {f2h(tile[kc + 0][nr]), f2h(tile[kc + 1][nr]),
                     f2h(tile[kc + 2][nr]), f2h(tile[kc + 3][nr])};
        *(ushort4*)(dst + (size_t)(tn + nr) * D_ + tk + kc) = o;
    }
}

// ---------------------------------------------------------------------------
// QKV projection, Z-FUSED: one block computes Q, K and V 128x64 tiles for
// its (m0,n0) -- As staged ONCE per K-step, reused for 3 weight tiles.
// Per wave per K-step: 48 MFMA vs 10 dma (was 16:6 unfused): 3x arithmetic
// intensity per barrier region; X L2 readers drop 36 -> 12 per panel.
// Single-buffer (R1/R5-proven), 768 blocks = 3/CU, LDS 40 KB, XCD swizzle.
// Q output pre-scaled by log2(e).
// ---------------------------------------------------------------------------
__global__ __launch_bounds__(256, 3) void gemm_qkv(
    const u16* __restrict__ Xh, const u16* __restrict__ Wt,
    const float* __restrict__ bq, const float* __restrict__ bk,
    const float* __restrict__ bv, u16* __restrict__ Qf,
    u16* __restrict__ Kf, u16* __restrict__ Vt) {
    __shared__ __align__(16) u16 As[128 * 64];      // 16 KB
    __shared__ __align__(16) u16 Bs[3 * 64 * 64];   // 24 KB (Wq|Wk|Wv tiles)

    const int id  = blockIdx.x;                  // 768
    const int xcd = id & 7, idx = id >> 3;       // 96 per XCD
    const int m0  = (xcd * 8 + idx / 12) * 128;  // XCD owns 8 m-panels
    const int n0  = (idx % 12) * 64;

    const int t = threadIdx.x, lane = t & 63, w = t >> 6;
    const int wm = w >> 1, wn = w & 1;
    const int quad = lane >> 4, ln = lane & 15;
    const int drow = lane >> 3, dcl = (lane & 7) ^ ((lane >> 3) & 7);

    f32x4 acc[3][4][2] = {};
    for (int k0 = 0; k0 < D_; k0 += 64) {
        __syncthreads();
#pragma unroll
        for (int j = 0; j < 4; ++j) {
            int i = w * 4 + j, row = i * 8 + drow;
            dma16(Xh + (size_t)(m0 + row) * D_ + k0 + dcl * 8, &As[i * 512]);
        }
#pragma unroll
        for (int z = 0; z < 3; ++z)
#pragma unroll
            for (int j = 0; j < 2; ++j) {
                int i = w * 2 + j, row = i * 8 + drow;
                dma16(Wt + (size_t)z * WELEM + (size_t)(n0 + row) * D_ + k0 + dcl * 8,
                      &Bs[z * 4096 + i * 512]);
            }
        __syncthreads();
        f16x8 a[4][2];
#pragma unroll
        for (int mt = 0; mt < 4; ++mt)
#pragma unroll
            for (int ks = 0; ks < 2; ++ks)
                a[mt][ks] = *(const f16x8*)&As[(wm * 64 + mt * 16 + ln) * 64 +
                                               (((ks * 4 + quad) ^ (ln & 7)) * 8)];
#pragma unroll
        for (int z = 0; z < 3; ++z) {
            f16x8 b[2][2];
#pragma unroll
            for (int nt = 0; nt < 2; ++nt)
#pragma unroll
                for (int ks = 0; ks < 2; ++ks)
                    b[nt][ks] = *(const f16x8*)&Bs[z * 4096 +
                                                   (wn * 32 + nt * 16 + ln) * 64 +
                                                   (((ks * 4 + quad) ^ (ln & 7)) * 8)];
#pragma unroll
            for (int mt = 0; mt < 4; ++mt)
#pragma unroll
                for (int nt = 0; nt < 2; ++nt) {
                    acc[z][mt][nt] = __builtin_amdgcn_mfma_f32_16x16x32_f16(
                        a[mt][0], b[nt][0], acc[z][mt][nt], 0, 0, 0);
                    acc[z][mt][nt] = __builtin_amdgcn_mfma_f32_16x16x32_f16(
                        a[mt][1], b[nt][1], acc[z][mt][nt], 0, 0, 0);
                }
        }
    }
    const int h = n0 >> 6;
#pragma unroll
    for (int nt = 0; nt < 2; ++nt) {
        int hd = wn * 32 + nt * 16 + ln;
        float bq_ = bq[n0 + hd], bk_ = bk[n0 + hd], bv_ = bv[n0 + hd];
#pragma unroll
        for (int mt = 0; mt < 4; ++mt) {
            int mb = m0 + wm * 64 + mt * 16 + quad * 4;
            int bb = mb >> 10, ns = mb & 1023;
#pragma unroll
            for (int r = 0; r < 4; ++r)
                Qf[(((size_t)bb * H_ + h) * N_ + ns + r) * HD_ + hd] =
                    f2h((acc[0][mt][nt][r] + bq_) * LOG2E_);
#pragma unroll
            for (int r = 0; r < 4; ++r)
                Kf[(((size_t)bb * H_ + h) * N_ + ns + r) * HD_ + hd] =
                    f2h(acc[1][mt][nt][r] + bk_);
            ushort4 o = {f2bf(acc[2][mt][nt][0] + bv_), f2bf(acc[2][mt][nt][1] + bv_),
                         f2bf(acc[2][mt][nt][2] + bv_), f2bf(acc[2][mt][nt][3] + bv_)};
            *(ushort4*)(Vt + (((size_t)bb * H_ + h) * HD_ + hd) * N_ + ns) = o;
        }
    }
}

// ---------------------------------------------------------------------------
// Flash attention, MFMA. v4 (R5-proven): 8 WAVES x 16 q-rows (512 threads),
// QBLK=128 / KVBLK=64 / LDS 50 KB (3 blocks/CU -> 6 waves/SIMD). Pipeline:
// prefetch-before-wait, counted vmcnt(2), 2 barriers/kt.
// ---------------------------------------------------------------------------
__global__ __launch_bounds__(512, 6) void attn_mfma(
    const u16* __restrict__ Qg, const u16* __restrict__ Kg,
    const u16* __restrict__ Vtg, u16* __restrict__ Og) {
    __shared__ __align__(16) u16 Ks[2][64 * 64];  // f16, rows permuted by g(rho)
    __shared__ __align__(16) u16 Vs[2][64 * 64];  // bf16 [hd][key], swizzled
    __shared__ __align__(16) u16 Ps[128 * 72];    // bf16 [q][key], wave-private rows

    const int t = threadIdx.x, lane = t & 63, w = t >> 6;   // w in 0..7
    const int quad = lane >> 4, ln = lane & 15;
    const int drow = lane >> 3, dcl = (lane & 7) ^ ((lane >> 3) & 7);
    const int id  = blockIdx.x;                  // 768
    const int id2 = (id & 7) * 96 + (id >> 3);
    const int bh  = id2 >> 3, qt = id2 & 7;
    const u16* Qh  = Qg  + ((size_t)bh * N_ + qt * 128) * HD_;
    const u16* Kh  = Kg  + (size_t)bh * N_ * HD_;
    const u16* Vth = Vtg + (size_t)bh * HD_ * N_;
    u16*       Oh  = Og  + ((size_t)bh * N_ + qt * 128) * HD_;

    const int rho = w * 8 + drow;                // 0..63: K-group / V-hd row
    const int gk  = 4 * (rho & 15) + (rho >> 4); // K row permutation

    f16x8 aq[2];
#pragma unroll
    for (int ks = 0; ks < 2; ++ks)
        aq[ks] = *(const f16x8*)(Qh + (size_t)(w * 16 + ln) * HD_ +
                                 ks * 32 + quad * 8);

    float lsum[4] = {};
    f32x4 oacc[4] = {};

    // prologue: stage kt=0 into buffer 0 (1 K-dma + 1 V-dma per wave)
    dma16(Kh + (size_t)gk * HD_ + dcl * 8, &Ks[0][w * 512]);
    dma16(Vth + (size_t)rho * N_ + dcl * 8, &Vs[0][w * 512]);

#pragma unroll 2
    for (int kt = 0; kt < 16; ++kt) {
        const int cur = kt & 1;
        if (kt < 15) {
            const int nk = (kt + 1) * 64;
            dma16(Kh + (size_t)(nk + gk) * HD_ + dcl * 8, &Ks[cur ^ 1][w * 512]);
            dma16(Vth + (size_t)rho * N_ + nk + dcl * 8, &Vs[cur ^ 1][w * 512]);
            asm volatile("s_waitcnt vmcnt(2)" ::: "memory");
        } else {
            asm volatile("s_waitcnt vmcnt(0)" ::: "memory");
        }
        __builtin_amdgcn_s_barrier();
        __builtin_amdgcn_sched_barrier(0);

        // S = Q K^T; D col ln of sub-tile nt = global key 4*ln+nt
        f32x4 sf[4];
        __builtin_amdgcn_s_setprio(1);
#pragma unroll
        for (int nt = 0; nt < 4; ++nt) {
            f16x8 b0 = *(const f16x8*)&Ks[cur][(nt * 16 + ln) * 64 + ((quad) ^ (ln & 7)) * 8];
            f16x8 b1 = *(const f16x8*)&Ks[cur][(nt * 16 + ln) * 64 + ((4 + quad) ^ (ln & 7)) * 8];
            f32x4 zz = {};
            sf[nt] = __builtin_amdgcn_mfma_f32_16x16x32_f16(aq[0], b0, zz, 0, 0, 0);
            sf[nt] = __builtin_amdgcn_mfma_f32_16x16x32_f16(aq[1], b1, sf[nt], 0, 0, 0);
        }
        __builtin_amdgcn_s_setprio(0);

        // p = exp2(s' - 20*log2e); pack 4 keys -> one b64 LDS write
#pragma unroll
        for (int r = 0; r < 4; ++r) {
            float e0 = EXP2F(sf[0][r] - EXPBIAS_);
            float e1 = EXP2F(sf[1][r] - EXPBIAS_);
            float e2 = EXP2F(sf[2][r] - EXPBIAS_);
            float e3 = EXP2F(sf[3][r] - EXPBIAS_);
            uint2 pk;
            pk.x = cvtpk_bf16(e0, e1);
            pk.y = cvtpk_bf16(e2, e3);
            int q = w * 16 + quad * 4 + r;
            *(uint2*)&Ps[q * 72 + ln * 4] = pk;
            lsum[r] += __uint_as_float(pk.x << 16) +
                       __uint_as_float(pk.x & 0xffff0000u) +
                       __uint_as_float(pk.y << 16) +
                       __uint_as_float(pk.y & 0xffff0000u);
        }

        // O += P V
        __builtin_amdgcn_s_setprio(1);
        {
            bf16x8 ap0 = *(const bf16x8*)&Ps[(w * 16 + ln) * 72 + quad * 8];
            bf16x8 ap1 = *(const bf16x8*)&Ps[(w * 16 + ln) * 72 + 32 + quad * 8];
#pragma unroll
            for (int nt = 0; nt < 4; ++nt) {
                bf16x8 bv0 = *(const bf16x8*)&Vs[cur][(nt * 16 + ln) * 64 +
                                                      ((quad ^ (ln & 7)) * 8)];
                oacc[nt] = __builtin_amdgcn_mfma_f32_16x16x32_bf16(
                    ap0, bv0, oacc[nt], 0, 0, 0);
                bf16x8 bv1 = *(const bf16x8*)&Vs[cur][(nt * 16 + ln) * 64 +
                                                      (((4 + quad) ^ (ln & 7)) * 8)];
                oacc[nt] = __builtin_amdgcn_mfma_f32_16x16x32_bf16(
                    ap1, bv1, oacc[nt], 0, 0, 0);
            }
        }
        __builtin_amdgcn_s_setprio(0);
        __builtin_amdgcn_sched_barrier(0);
        __builtin_amdgcn_s_barrier();   // all waves done reading buf[cur]
    }

    const float sc = 0.036084391824351615f;  // 1/sqrt(768), AFTER softmax
#pragma unroll
    for (int r = 0; r < 4; ++r) {
        float l = lsum[r];
        l += __shfl_xor(l, 1);
        l += __shfl_xor(l, 2);
        l += __shfl_xor(l, 4);
        l += __shfl_xor(l, 8);
        float inv = sc / l;
#pragma unroll
        for (int nt = 0; nt < 4; ++nt)
            Oh[(size_t)(w * 16 + quad * 4 + r) * HD_ + nt * 16 + ln] =
                f2h(oacc[nt][r] * inv);
    }
}

// ---------------------------------------------------------------------------
// Output projection: out = O @ Wo + bo. 128x64 single-buffer (R1-proven)
// + XCD swizzle. 768 = 3 blocks/CU.
// ---------------------------------------------------------------------------
__global__ __launch_bounds__(256) void gemm_out(
    const u16* __restrict__ Ob, const u16* __restrict__ Wto,
    const float* __restrict__ bias, float* __restrict__ Out) {
    __shared__ __align__(16) u16 As[128 * 64];
    __shared__ __align__(16) u16 Bs[64 * 64];

    const int id  = blockIdx.x;                  // 768
    const int id2 = (id & 7) * 96 + (id >> 3);
    const int m0  = (id2 / 12) * 128, n0 = (id2 % 12) * 64;

    const int t = threadIdx.x, lane = t & 63, w = t >> 6;
    const int wm = w >> 1, wn = w & 1;
    const int quad = lane >> 4, ln = lane & 15;
    const int drow = lane >> 3, dcl = (lane & 7) ^ ((lane >> 3) & 7);

    f32x4 acc[4][2] = {};
    for (int k0 = 0; k0 < D_; k0 += 64) {
        int head = k0 >> 6;
        __syncthreads();
#pragma unroll
        for (int j = 0; j < 4; ++j) {
            int i = w * 4 + j, row = i * 8 + drow;
            int m = m0 + row, bb = m >> 10, ns = m & 1023;
            dma16(Ob + (((size_t)bb * H_ + head) * N_ + ns) * HD_ + dcl * 8, &As[i * 512]);
        }
#pragma unroll
        for (int j = 0; j < 2; ++j) {
            int i = w * 2 + j, row = i * 8 + drow;
            dma16(Wto + (size_t)(n0 + row) * D_ + k0 + dcl * 8, &Bs[i * 512]);
        }
        __syncthreads();
        f16x8 a[4][2], b[2][2];
#pragma unroll
        for (int mt = 0; mt < 4; ++mt)
#pragma unroll
            for (int ks = 0; ks < 2; ++ks)
                a[mt][ks] = *(const f16x8*)&As[(wm * 64 + mt * 16 + ln) * 64 +
                                               (((ks * 4 + quad) ^ (ln & 7)) * 8)];
#pragma unroll
        for (int nt = 0; nt < 2; ++nt)
#pragma unroll
            for (int ks = 0; ks < 2; ++ks)
                b[nt][ks] = *(const f16x8*)&Bs[(wn * 32 + nt * 16 + ln) * 64 +
                                               (((ks * 4 + quad) ^ (ln & 7)) * 8)];
#pragma unroll
        for (int mt = 0; mt < 4; ++mt)
#pragma unroll
            for (int nt = 0; nt < 2; ++nt) {
                acc[mt][nt] = __builtin_amdgcn_mfma_f32_16x16x32_f16(
                    a[mt][0], b[nt][0], acc[mt][nt], 0, 0, 0);
                acc[mt][nt] = __builtin_amdgcn_mfma_f32_16x16x32_f16(
                    a[mt][1], b[nt][1], acc[mt][nt], 0, 0, 0);
            }
    }
#pragma unroll
    for (int nt = 0; nt < 2; ++nt) {
        int n = n0 + wn * 32 + nt * 16 + ln;
        float bv_ = bias[n];
#pragma unroll
        for (int mt = 0; mt < 4; ++mt) {
            int mb = m0 + wm * 64 + mt * 16 + quad * 4;
#pragma unroll
            for (int r = 0; r < 4; ++r)
                Out[(size_t)(mb + r) * D_ + n] = acc[mt][nt][r] + bv_;
        }
    }
}

extern "C" void kernel_launch(void* const* d_in, const int* in_sizes, int n_in,
                              void* d_out, int out_size, void* d_ws, size_t ws_size,
                              hipStream_t stream) {
    const float* x  = (const float*)d_in[0];
    const float* Wq = (const float*)d_in[1];
    const float* bq = (const float*)d_in[2];
    const float* Wk = (const float*)d_in[3];
    const float* bk = (const float*)d_in[4];
    const float* Wv = (const float*)d_in[5];
    const float* bv = (const float*)d_in[6];
    const float* Wo = (const float*)d_in[7];
    const float* bo = (const float*)d_in[8];

    u16* Xh = (u16*)d_ws;                  // x f16, 12.6 MB
    u16* Wt = Xh + XELEM;                  // 4 W^T f16
    u16* Qf = Wt + 4 * (size_t)WELEM;      // Q f16 (B,H,N,HD), pre-scaled by log2e
    u16* Kf = Qf + XELEM;                  // K f16 (B,H,N,HD)
    u16* Vt = Kf + XELEM;                  // V bf16 (B,H,HD,N)
    u16* Ob = Vt + XELEM;                  // attn out f16 (B,H,N,HD)

    cvt_x<<<dim3((int)(XELEM / 4 / 256)), 256, 0, stream>>>(x, Xh);
    cvt_w<<<dim3(144, 4), 256, 0, stream>>>(Wq, Wk, Wv, Wo, Wt);
    gemm_qkv<<<dim3(768), 256, 0, stream>>>(Xh, Wt, bq, bk, bv, Qf, Kf, Vt);
    attn_mfma<<<dim3(768), 512, 0, stream>>>(Qf, Kf, Vt, Ob);
    gemm_out<<<dim3(768), 256, 0, stream>>>(
        Ob, Wt + 3 * (size_t)WELEM, bo, (float*)d_out);
}

// Round 7
// 183.513 us; speedup vs baseline: 1.1609x; 1.0240x over previous
//
#include <hip/hip_runtime.h>

#define B_  8
#define N_  1024
#define D_  768
#define H_  12
#define HD_ 64
#define M_  (B_ * N_)            // 8192
#define WELEM (D_ * D_)          // 589824
#define XELEM ((size_t)M_ * D_)  // 6291456

typedef _Float16 f16;
typedef f16   f16x8  __attribute__((ext_vector_type(8)));
typedef short bf16x8 __attribute__((ext_vector_type(8)));
typedef float f32x4  __attribute__((ext_vector_type(4)));
typedef unsigned short u16;

__device__ __forceinline__ u16 f2bf(float f) {
    unsigned int x = __float_as_uint(f);
    return (u16)((x + 0x7fffu + ((x >> 16) & 1u)) >> 16);   // RNE
}
__device__ __forceinline__ u16 f2h(float f) {
    return __builtin_bit_cast(u16, (f16)f);                 // RNE
}
// packed f32x2 -> bf16x2 in one VALU op
__device__ __forceinline__ unsigned int cvtpk_bf16(float lo, float hi) {
    unsigned int r;
    asm("v_cvt_pk_bf16_f32 %0, %1, %2" : "=v"(r) : "v"(lo), "v"(hi));
    return r;
}
#if __has_builtin(__builtin_amdgcn_exp2f)
#define EXP2F(x) __builtin_amdgcn_exp2f(x)
#else
#define EXP2F(x) exp2f(x)
#endif

#define LOG2E_   1.4426950408889634f
#define EXPBIAS_ 28.853900817779268f   // 20 * log2(e)

// direct global->LDS DMA, 16B per lane; dst = wave-uniform base + lane*16
typedef __attribute__((address_space(3))) unsigned int       as3_u32;
typedef __attribute__((address_space(1))) const unsigned int as1_u32;
__device__ __forceinline__ void dma16(const void* g, void* l) {
    __builtin_amdgcn_global_load_lds((as1_u32*)g, (as3_u32*)l, 16, 0, 0);
}

// ---------------------------------------------------------------------------
// x (fp32, M x D) -> f16, same layout.
// ---------------------------------------------------------------------------
__global__ __launch_bounds__(256) void cvt_x(const float* __restrict__ X,
                                             u16* __restrict__ Xh) {
    int idx = blockIdx.x * 256 + threadIdx.x;
    float4 v = ((const float4*)X)[idx];
    ushort4 o = {f2h(v.x), f2h(v.y), f2h(v.z), f2h(v.w)};
    ((ushort4*)Xh)[idx] = o;
}

// ---------------------------------------------------------------------------
// W (fp32, [k][n]) -> Wt (f16, [n][k]) for all 4 weights. 64x64 tiles.
// ---------------------------------------------------------------------------
__global__ __launch_bounds__(256) void cvt_w(
    const float* __restrict__ w0, const float* __restrict__ w1,
    const float* __restrict__ w2, const float* __restrict__ w3,
    u16* __restrict__ Wt) {
    const float* W = blockIdx.y == 0 ? w0 : blockIdx.y == 1 ? w1
                   : blockIdx.y == 2 ? w2 : w3;
    u16* dst = Wt + (size_t)blockIdx.y * WELEM;
    const int t  = threadIdx.x;
    const int tk = (blockIdx.x % 12) * 64, tn = (blockIdx.x / 12) * 64;
    __shared__ __align__(16) float tile[64][68];
#pragma unroll
    for (int i = 0; i < 4; ++i) {
        int r = (t >> 4) + i * 16, c4 = (t & 15) * 4;
        float4 v = *(const float4*)(W + (size_t)(tk + r) * D_ + tn + c4);
        *(float4*)&tile[r][c4] = v;
    }
    __syncthreads();
#pragma unroll
    for (int i = 0; i < 4; ++i) {
        int nr = (t >> 4) + i * 16, kc = (t & 15) * 4;
        ushort4 o = {f2h(tile[kc + 0][nr]), f2h(tile[kc + 1][nr]),
                     f2h(tile[kc + 2][nr]), f2h(tile[kc + 3][nr])};
        *(ushort4*)(dst + (size_t)(tn + nr) * D_ + tk + kc) = o;
    }
}

// ---------------------------------------------------------------------------
// QKV projection, Z-FUSED (R6-proven): one block computes Q, K and V 128x64
// tiles for its (m0,n0) -- As staged ONCE per K-step, reused for 3 W tiles.
// Single-buffer, 768 blocks = 3/CU, LDS 40 KB, XCD swizzle.
// Q output pre-scaled by log2(e).
// ---------------------------------------------------------------------------
__global__ __launch_bounds__(256, 3) void gemm_qkv(
    const u16* __restrict__ Xh, const u16* __restrict__ Wt,
    const float* __restrict__ bq, const float* __restrict__ bk,
    const float* __restrict__ bv, u16* __restrict__ Qf,
    u16* __restrict__ Kf, u16* __restrict__ Vt) {
    __shared__ __align__(16) u16 As[128 * 64];      // 16 KB
    __shared__ __align__(16) u16 Bs[3 * 64 * 64];   // 24 KB (Wq|Wk|Wv tiles)

    const int id  = blockIdx.x;                  // 768
    const int xcd = id & 7, idx = id >> 3;       // 96 per XCD
    const int m0  = (xcd * 8 + idx / 12) * 128;  // XCD owns 8 m-panels
    const int n0  = (idx % 12) * 64;

    const int t = threadIdx.x, lane = t & 63, w = t >> 6;
    const int wm = w >> 1, wn = w & 1;
    const int quad = lane >> 4, ln = lane & 15;
    const int drow = lane >> 3, dcl = (lane & 7) ^ ((lane >> 3) & 7);

    f32x4 acc[3][4][2] = {};
    for (int k0 = 0; k0 < D_; k0 += 64) {
        __syncthreads();
#pragma unroll
        for (int j = 0; j < 4; ++j) {
            int i = w * 4 + j, row = i * 8 + drow;
            dma16(Xh + (size_t)(m0 + row) * D_ + k0 + dcl * 8, &As[i * 512]);
        }
#pragma unroll
        for (int z = 0; z < 3; ++z)
#pragma unroll
            for (int j = 0; j < 2; ++j) {
                int i = w * 2 + j, row = i * 8 + drow;
                dma16(Wt + (size_t)z * WELEM + (size_t)(n0 + row) * D_ + k0 + dcl * 8,
                      &Bs[z * 4096 + i * 512]);
            }
        __syncthreads();
        f16x8 a[4][2];
#pragma unroll
        for (int mt = 0; mt < 4; ++mt)
#pragma unroll
            for (int ks = 0; ks < 2; ++ks)
                a[mt][ks] = *(const f16x8*)&As[(wm * 64 + mt * 16 + ln) * 64 +
                                               (((ks * 4 + quad) ^ (ln & 7)) * 8)];
#pragma unroll
        for (int z = 0; z < 3; ++z) {
            f16x8 b[2][2];
#pragma unroll
            for (int nt = 0; nt < 2; ++nt)
#pragma unroll
                for (int ks = 0; ks < 2; ++ks)
                    b[nt][ks] = *(const f16x8*)&Bs[z * 4096 +
                                                   (wn * 32 + nt * 16 + ln) * 64 +
                                                   (((ks * 4 + quad) ^ (ln & 7)) * 8)];
#pragma unroll
            for (int mt = 0; mt < 4; ++mt)
#pragma unroll
                for (int nt = 0; nt < 2; ++nt) {
                    acc[z][mt][nt] = __builtin_amdgcn_mfma_f32_16x16x32_f16(
                        a[mt][0], b[nt][0], acc[z][mt][nt], 0, 0, 0);
                    acc[z][mt][nt] = __builtin_amdgcn_mfma_f32_16x16x32_f16(
                        a[mt][1], b[nt][1], acc[z][mt][nt], 0, 0, 0);
                }
        }
    }
    const int h = n0 >> 6;
#pragma unroll
    for (int nt = 0; nt < 2; ++nt) {
        int hd = wn * 32 + nt * 16 + ln;
        float bq_ = bq[n0 + hd], bk_ = bk[n0 + hd], bv_ = bv[n0 + hd];
#pragma unroll
        for (int mt = 0; mt < 4; ++mt) {
            int mb = m0 + wm * 64 + mt * 16 + quad * 4;
            int bb = mb >> 10, ns = mb & 1023;
#pragma unroll
            for (int r = 0; r < 4; ++r)
                Qf[(((size_t)bb * H_ + h) * N_ + ns + r) * HD_ + hd] =
                    f2h((acc[0][mt][nt][r] + bq_) * LOG2E_);
#pragma unroll
            for (int r = 0; r < 4; ++r)
                Kf[(((size_t)bb * H_ + h) * N_ + ns + r) * HD_ + hd] =
                    f2h(acc[1][mt][nt][r] + bk_);
            ushort4 o = {f2bf(acc[2][mt][nt][0] + bv_), f2bf(acc[2][mt][nt][1] + bv_),
                         f2bf(acc[2][mt][nt][2] + bv_), f2bf(acc[2][mt][nt][3] + bv_)};
            *(ushort4*)(Vt + (((size_t)bb * H_ + h) * HD_ + hd) * N_ + ns) = o;
        }
    }
}

// ---------------------------------------------------------------------------
// Flash attention, MFMA. v5: 8 waves x 16 q-rows (R5/R6-proven structure:
// prefetch-before-wait, counted vmcnt(2), 2 barriers/kt) + VALU cuts:
//  - exp bias folded into QK^T C-init (nb): -16 v_sub/kt/wave  [R2-verified]
//  - lsum on MFMA pipe via P x ones (lacc): -32 VALU/kt/wave and no
//    epilogue shfl-reduce; lane's lacc[r] lands exactly at its O-row
//    (C-layout row=quad*4+r, cols equal)                       [R2-verified]
// VALU was the widest pipe (42% vs MFMA 23%) -> trade VALU for MFMA slack.
// ---------------------------------------------------------------------------
__global__ __launch_bounds__(512, 6) void attn_mfma(
    const u16* __restrict__ Qg, const u16* __restrict__ Kg,
    const u16* __restrict__ Vtg, u16* __restrict__ Og) {
    __shared__ __align__(16) u16 Ks[2][64 * 64];  // f16, rows permuted by g(rho)
    __shared__ __align__(16) u16 Vs[2][64 * 64];  // bf16 [hd][key], swizzled
    __shared__ __align__(16) u16 Ps[128 * 72];    // bf16 [q][key], wave-private rows

    const int t = threadIdx.x, lane = t & 63, w = t >> 6;   // w in 0..7
    const int quad = lane >> 4, ln = lane & 15;
    const int drow = lane >> 3, dcl = (lane & 7) ^ ((lane >> 3) & 7);
    const int id  = blockIdx.x;                  // 768
    const int id2 = (id & 7) * 96 + (id >> 3);
    const int bh  = id2 >> 3, qt = id2 & 7;
    const u16* Qh  = Qg  + ((size_t)bh * N_ + qt * 128) * HD_;
    const u16* Kh  = Kg  + (size_t)bh * N_ * HD_;
    const u16* Vth = Vtg + (size_t)bh * HD_ * N_;
    u16*       Oh  = Og  + ((size_t)bh * N_ + qt * 128) * HD_;

    const int rho = w * 8 + drow;                // 0..63: K-group / V-hd row
    const int gk  = 4 * (rho & 15) + (rho >> 4); // K row permutation

    f16x8 aq[2];
#pragma unroll
    for (int ks = 0; ks < 2; ++ks)
        aq[ks] = *(const f16x8*)(Qh + (size_t)(w * 16 + ln) * HD_ +
                                 ks * 32 + quad * 8);

    const bf16x8 pone = {0x3F80, 0x3F80, 0x3F80, 0x3F80,
                         0x3F80, 0x3F80, 0x3F80, 0x3F80};   // bf16 1.0 x8
    const f32x4 nb = {-EXPBIAS_, -EXPBIAS_, -EXPBIAS_, -EXPBIAS_};

    f32x4 oacc[4] = {};
    f32x4 lacc = {};

    // prologue: stage kt=0 into buffer 0 (1 K-dma + 1 V-dma per wave)
    dma16(Kh + (size_t)gk * HD_ + dcl * 8, &Ks[0][w * 512]);
    dma16(Vth + (size_t)rho * N_ + dcl * 8, &Vs[0][w * 512]);

#pragma unroll 2
    for (int kt = 0; kt < 16; ++kt) {
        const int cur = kt & 1;
        // issue next tile's loads into the other buffer (last read at kt-1,
        // one full barrier behind -> safe), then wait only for the CURRENT
        // buffer's 2 loads: the 2 newer stay in flight across the barrier.
        if (kt < 15) {
            const int nk = (kt + 1) * 64;
            dma16(Kh + (size_t)(nk + gk) * HD_ + dcl * 8, &Ks[cur ^ 1][w * 512]);
            dma16(Vth + (size_t)rho * N_ + nk + dcl * 8, &Vs[cur ^ 1][w * 512]);
            asm volatile("s_waitcnt vmcnt(2)" ::: "memory");
        } else {
            asm volatile("s_waitcnt vmcnt(0)" ::: "memory");
        }
        __builtin_amdgcn_s_barrier();
        __builtin_amdgcn_sched_barrier(0);

        // S = Q K^T - 20*log2e (bias folded into C-init);
        // D col ln of sub-tile nt = global key 4*ln+nt
        f32x4 sf[4];
        __builtin_amdgcn_s_setprio(1);
#pragma unroll
        for (int nt = 0; nt < 4; ++nt) {
            f16x8 b0 = *(const f16x8*)&Ks[cur][(nt * 16 + ln) * 64 + ((quad) ^ (ln & 7)) * 8];
            f16x8 b1 = *(const f16x8*)&Ks[cur][(nt * 16 + ln) * 64 + ((4 + quad) ^ (ln & 7)) * 8];
            sf[nt] = __builtin_amdgcn_mfma_f32_16x16x32_f16(aq[0], b0, nb, 0, 0, 0);
            sf[nt] = __builtin_amdgcn_mfma_f32_16x16x32_f16(aq[1], b1, sf[nt], 0, 0, 0);
        }
        __builtin_amdgcn_s_setprio(0);

        // p = exp2(s'); pack 4 contiguous keys -> one b64 LDS write
#pragma unroll
        for (int r = 0; r < 4; ++r) {
            float e0 = EXP2F(sf[0][r]);
            float e1 = EXP2F(sf[1][r]);
            float e2 = EXP2F(sf[2][r]);
            float e3 = EXP2F(sf[3][r]);
            uint2 pk;
            pk.x = cvtpk_bf16(e0, e1);
            pk.y = cvtpk_bf16(e2, e3);
            int q = w * 16 + quad * 4 + r;
            *(uint2*)&Ps[q * 72 + ln * 4] = pk;
        }

        // O += P V ; lsum += P x ones (row-sum of ROUNDED P on the MFMA pipe;
        // independent lacc chain, not on the oacc critical path)
        __builtin_amdgcn_s_setprio(1);
        {
            bf16x8 ap0 = *(const bf16x8*)&Ps[(w * 16 + ln) * 72 + quad * 8];
            bf16x8 ap1 = *(const bf16x8*)&Ps[(w * 16 + ln) * 72 + 32 + quad * 8];
            lacc = __builtin_amdgcn_mfma_f32_16x16x32_bf16(ap0, pone, lacc, 0, 0, 0);
            lacc = __builtin_amdgcn_mfma_f32_16x16x32_bf16(ap1, pone, lacc, 0, 0, 0);
#pragma unroll
            for (int nt = 0; nt < 4; ++nt) {
                bf16x8 bv0 = *(const bf16x8*)&Vs[cur][(nt * 16 + ln) * 64 +
                                                      ((quad ^ (ln & 7)) * 8)];
                oacc[nt] = __builtin_amdgcn_mfma_f32_16x16x32_bf16(
                    ap0, bv0, oacc[nt], 0, 0, 0);
                bf16x8 bv1 = *(const bf16x8*)&Vs[cur][(nt * 16 + ln) * 64 +
                                                      (((4 + quad) ^ (ln & 7)) * 8)];
                oacc[nt] = __builtin_amdgcn_mfma_f32_16x16x32_bf16(
                    ap1, bv1, oacc[nt], 0, 0, 0);
            }
        }
        __builtin_amdgcn_s_setprio(0);
        __builtin_amdgcn_sched_barrier(0);
        __builtin_amdgcn_s_barrier();   // all waves done reading buf[cur]
    }

    const float sc = 0.036084391824351615f;  // 1/sqrt(768), AFTER softmax
#pragma unroll
    for (int r = 0; r < 4; ++r) {
        float inv = sc / lacc[r];        // lane's row q = w*16+quad*4+r
#pragma unroll
        for (int nt = 0; nt < 4; ++nt)
            Oh[(size_t)(w * 16 + quad * 4 + r) * HD_ + nt * 16 + ln] =
                f2h(oacc[nt][r] * inv);
    }
}

// ---------------------------------------------------------------------------
// Output projection: out = O @ Wo + bo. 128x64 single-buffer (R1-proven)
// + XCD swizzle. 768 = 3 blocks/CU.
// ---------------------------------------------------------------------------
__global__ __launch_bounds__(256) void gemm_out(
    const u16* __restrict__ Ob, const u16* __restrict__ Wto,
    const float* __restrict__ bias, float* __restrict__ Out) {
    __shared__ __align__(16) u16 As[128 * 64];
    __shared__ __align__(16) u16 Bs[64 * 64];

    const int id  = blockIdx.x;                  // 768
    const int id2 = (id & 7) * 96 + (id >> 3);
    const int m0  = (id2 / 12) * 128, n0 = (id2 % 12) * 64;

    const int t = threadIdx.x, lane = t & 63, w = t >> 6;
    const int wm = w >> 1, wn = w & 1;
    const int quad = lane >> 4, ln = lane & 15;
    const int drow = lane >> 3, dcl = (lane & 7) ^ ((lane >> 3) & 7);

    f32x4 acc[4][2] = {};
    for (int k0 = 0; k0 < D_; k0 += 64) {
        int head = k0 >> 6;
        __syncthreads();
#pragma unroll
        for (int j = 0; j < 4; ++j) {
            int i = w * 4 + j, row = i * 8 + drow;
            int m = m0 + row, bb = m >> 10, ns = m & 1023;
            dma16(Ob + (((size_t)bb * H_ + head) * N_ + ns) * HD_ + dcl * 8, &As[i * 512]);
        }
#pragma unroll
        for (int j = 0; j < 2; ++j) {
            int i = w * 2 + j, row = i * 8 + drow;
            dma16(Wto + (size_t)(n0 + row) * D_ + k0 + dcl * 8, &Bs[i * 512]);
        }
        __syncthreads();
        f16x8 a[4][2], b[2][2];
#pragma unroll
        for (int mt = 0; mt < 4; ++mt)
#pragma unroll
            for (int ks = 0; ks < 2; ++ks)
                a[mt][ks] = *(const f16x8*)&As[(wm * 64 + mt * 16 + ln) * 64 +
                                               (((ks * 4 + quad) ^ (ln & 7)) * 8)];
#pragma unroll
        for (int nt = 0; nt < 2; ++nt)
#pragma unroll
            for (int ks = 0; ks < 2; ++ks)
                b[nt][ks] = *(const f16x8*)&Bs[(wn * 32 + nt * 16 + ln) * 64 +
                                               (((ks * 4 + quad) ^ (ln & 7)) * 8)];
#pragma unroll
        for (int mt = 0; mt < 4; ++mt)
#pragma unroll
            for (int nt = 0; nt < 2; ++nt) {
                acc[mt][nt] = __builtin_amdgcn_mfma_f32_16x16x32_f16(
                    a[mt][0], b[nt][0], acc[mt][nt], 0, 0, 0);
                acc[mt][nt] = __builtin_amdgcn_mfma_f32_16x16x32_f16(
                    a[mt][1], b[nt][1], acc[mt][nt], 0, 0, 0);
            }
    }
#pragma unroll
    for (int nt = 0; nt < 2; ++nt) {
        int n = n0 + wn * 32 + nt * 16 + ln;
        float bv_ = bias[n];
#pragma unroll
        for (int mt = 0; mt < 4; ++mt) {
            int mb = m0 + wm * 64 + mt * 16 + quad * 4;
#pragma unroll
            for (int r = 0; r < 4; ++r)
                Out[(size_t)(mb + r) * D_ + n] = acc[mt][nt][r] + bv_;
        }
    }
}

extern "C" void kernel_launch(void* const* d_in, const int* in_sizes, int n_in,
                              void* d_out, int out_size, void* d_ws, size_t ws_size,
                              hipStream_t stream) {
    const float* x  = (const float*)d_in[0];
    const float* Wq = (const float*)d_in[1];
    const float* bq = (const float*)d_in[2];
    const float* Wk = (const float*)d_in[3];
    const float* bk = (const float*)d_in[4];
    const float* Wv = (const float*)d_in[5];
    const float* bv = (const float*)d_in[6];
    const float* Wo = (const float*)d_in[7];
    const float* bo = (const float*)d_in[8];

    u16* Xh = (u16*)d_ws;                  // x f16, 12.6 MB
    u16* Wt = Xh + XELEM;                  // 4 W^T f16
    u16* Qf = Wt + 4 * (size_t)WELEM;      // Q f16 (B,H,N,HD), pre-scaled by log2e
    u16* Kf = Qf + XELEM;                  // K f16 (B,H,N,HD)
    u16* Vt = Kf + XELEM;                  // V bf16 (B,H,HD,N)
    u16* Ob = Vt + XELEM;                  // attn out f16 (B,H,N,HD)

    cvt_x<<<dim3((int)(XELEM / 4 / 256)), 256, 0, stream>>>(x, Xh);
    cvt_w<<<dim3(144, 4), 256, 0, stream>>>(Wq, Wk, Wv, Wo, Wt);
    gemm_qkv<<<dim3(768), 256, 0, stream>>>(Xh, Wt, bq, bk, bv, Qf, Kf, Vt);
    attn_mfma<<<dim3(768), 512, 0, stream>>>(Qf, Kf, Vt, Ob);
    gemm_out<<<dim3(768), 256, 0, stream>>>(
        Ob, Wt + 3 * (size_t)WELEM, bo, (float*)d_out);
}

// Round 8
// 179.735 us; speedup vs baseline: 1.1853x; 1.0210x over previous
//
#include <hip/hip_runtime.h>

#define B_  8
#define N_  1024
#define D_  768
#define H_  12
#define HD_ 64
#define M_  (B_ * N_)            // 8192
#define WELEM (D_ * D_)          // 589824
#define XELEM ((size_t)M_ * D_)  // 6291456

typedef _Float16 f16;
typedef f16   f16x8  __attribute__((ext_vector_type(8)));
typedef short bf16x8 __attribute__((ext_vector_type(8)));
typedef float f32x4  __attribute__((ext_vector_type(4)));
typedef unsigned short u16;

__device__ __forceinline__ u16 f2bf(float f) {
    unsigned int x = __float_as_uint(f);
    return (u16)((x + 0x7fffu + ((x >> 16) & 1u)) >> 16);   // RNE
}
__device__ __forceinline__ u16 f2h(float f) {
    return __builtin_bit_cast(u16, (f16)f);                 // RNE
}
// packed f32x2 -> bf16x2 in one VALU op
__device__ __forceinline__ unsigned int cvtpk_bf16(float lo, float hi) {
    unsigned int r;
    asm("v_cvt_pk_bf16_f32 %0, %1, %2" : "=v"(r) : "v"(lo), "v"(hi));
    return r;
}
#if __has_builtin(__builtin_amdgcn_exp2f)
#define EXP2F(x) __builtin_amdgcn_exp2f(x)
#else
#define EXP2F(x) exp2f(x)
#endif

#define LOG2E_   1.4426950408889634f
#define EXPBIAS_ 28.853900817779268f   // 20 * log2(e)

// direct global->LDS DMA, 16B per lane; dst = wave-uniform base + lane*16
typedef __attribute__((address_space(3))) unsigned int       as3_u32;
typedef __attribute__((address_space(1))) const unsigned int as1_u32;
__device__ __forceinline__ void dma16(const void* g, void* l) {
    __builtin_amdgcn_global_load_lds((as1_u32*)g, (as3_u32*)l, 16, 0, 0);
}

// ---------------------------------------------------------------------------
// x (fp32, M x D) -> f16, same layout.
// ---------------------------------------------------------------------------
__global__ __launch_bounds__(256) void cvt_x(const float* __restrict__ X,
                                             u16* __restrict__ Xh) {
    int idx = blockIdx.x * 256 + threadIdx.x;
    float4 v = ((const float4*)X)[idx];
    ushort4 o = {f2h(v.x), f2h(v.y), f2h(v.z), f2h(v.w)};
    ((ushort4*)Xh)[idx] = o;
}

// ---------------------------------------------------------------------------
// W (fp32, [k][n]) -> Wt (f16, [n][k]) for all 4 weights. 64x64 tiles.
// ---------------------------------------------------------------------------
__global__ __launch_bounds__(256) void cvt_w(
    const float* __restrict__ w0, const float* __restrict__ w1,
    const float* __restrict__ w2, const float* __restrict__ w3,
    u16* __restrict__ Wt) {
    const float* W = blockIdx.y == 0 ? w0 : blockIdx.y == 1 ? w1
                   : blockIdx.y == 2 ? w2 : w3;
    u16* dst = Wt + (size_t)blockIdx.y * WELEM;
    const int t  = threadIdx.x;
    const int tk = (blockIdx.x % 12) * 64, tn = (blockIdx.x / 12) * 64;
    __shared__ __align__(16) float tile[64][68];
#pragma unroll
    for (int i = 0; i < 4; ++i) {
        int r = (t >> 4) + i * 16, c4 = (t & 15) * 4;
        float4 v = *(const float4*)(W + (size_t)(tk + r) * D_ + tn + c4);
        *(float4*)&tile[r][c4] = v;
    }
    __syncthreads();
#pragma unroll
    for (int i = 0; i < 4; ++i) {
        int nr = (t >> 4) + i * 16, kc = (t & 15) * 4;
        ushort4 o = {f2h(tile[kc + 0][nr]), f2h(tile[kc + 1][nr]),
                     f2h(tile[kc + 2][nr]), f2h(tile[kc + 3][nr])};
        *(ushort4*)(dst + (size_t)(tn + nr) * D_ + tk + kc) = o;
    }
}

// ---------------------------------------------------------------------------
// QKV projection, Z-FUSED (R6-proven): one block computes Q, K and V 128x64
// tiles for its (m0,n0) -- As staged ONCE per K-step, reused for 3 W tiles.
// Single-buffer, 768 blocks = 3/CU, LDS 40 KB, XCD swizzle.
// Q output pre-scaled by log2(e).
// ---------------------------------------------------------------------------
__global__ __launch_bounds__(256, 3) void gemm_qkv(
    const u16* __restrict__ Xh, const u16* __restrict__ Wt,
    const float* __restrict__ bq, const float* __restrict__ bk,
    const float* __restrict__ bv, u16* __restrict__ Qf,
    u16* __restrict__ Kf, u16* __restrict__ Vt) {
    __shared__ __align__(16) u16 As[128 * 64];      // 16 KB
    __shared__ __align__(16) u16 Bs[3 * 64 * 64];   // 24 KB (Wq|Wk|Wv tiles)

    const int id  = blockIdx.x;                  // 768
    const int xcd = id & 7, idx = id >> 3;       // 96 per XCD
    const int m0  = (xcd * 8 + idx / 12) * 128;  // XCD owns 8 m-panels
    const int n0  = (idx % 12) * 64;

    const int t = threadIdx.x, lane = t & 63, w = t >> 6;
    const int wm = w >> 1, wn = w & 1;
    const int quad = lane >> 4, ln = lane & 15;
    const int drow = lane >> 3, dcl = (lane & 7) ^ ((lane >> 3) & 7);

    f32x4 acc[3][4][2] = {};
    for (int k0 = 0; k0 < D_; k0 += 64) {
        __syncthreads();
#pragma unroll
        for (int j = 0; j < 4; ++j) {
            int i = w * 4 + j, row = i * 8 + drow;
            dma16(Xh + (size_t)(m0 + row) * D_ + k0 + dcl * 8, &As[i * 512]);
        }
#pragma unroll
        for (int z = 0; z < 3; ++z)
#pragma unroll
            for (int j = 0; j < 2; ++j) {
                int i = w * 2 + j, row = i * 8 + drow;
                dma16(Wt + (size_t)z * WELEM + (size_t)(n0 + row) * D_ + k0 + dcl * 8,
                      &Bs[z * 4096 + i * 512]);
            }
        __syncthreads();
        f16x8 a[4][2];
#pragma unroll
        for (int mt = 0; mt < 4; ++mt)
#pragma unroll
            for (int ks = 0; ks < 2; ++ks)
                a[mt][ks] = *(const f16x8*)&As[(wm * 64 + mt * 16 + ln) * 64 +
                                               (((ks * 4 + quad) ^ (ln & 7)) * 8)];
#pragma unroll
        for (int z = 0; z < 3; ++z) {
            f16x8 b[2][2];
#pragma unroll
            for (int nt = 0; nt < 2; ++nt)
#pragma unroll
                for (int ks = 0; ks < 2; ++ks)
                    b[nt][ks] = *(const f16x8*)&Bs[z * 4096 +
                                                   (wn * 32 + nt * 16 + ln) * 64 +
                                                   (((ks * 4 + quad) ^ (ln & 7)) * 8)];
#pragma unroll
            for (int mt = 0; mt < 4; ++mt)
#pragma unroll
                for (int nt = 0; nt < 2; ++nt) {
                    acc[z][mt][nt] = __builtin_amdgcn_mfma_f32_16x16x32_f16(
                        a[mt][0], b[nt][0], acc[z][mt][nt], 0, 0, 0);
                    acc[z][mt][nt] = __builtin_amdgcn_mfma_f32_16x16x32_f16(
                        a[mt][1], b[nt][1], acc[z][mt][nt], 0, 0, 0);
                }
        }
    }
    const int h = n0 >> 6;
#pragma unroll
    for (int nt = 0; nt < 2; ++nt) {
        int hd = wn * 32 + nt * 16 + ln;
        float bq_ = bq[n0 + hd], bk_ = bk[n0 + hd], bv_ = bv[n0 + hd];
#pragma unroll
        for (int mt = 0; mt < 4; ++mt) {
            int mb = m0 + wm * 64 + mt * 16 + quad * 4;
            int bb = mb >> 10, ns = mb & 1023;
#pragma unroll
            for (int r = 0; r < 4; ++r)
                Qf[(((size_t)bb * H_ + h) * N_ + ns + r) * HD_ + hd] =
                    f2h((acc[0][mt][nt][r] + bq_) * LOG2E_);
#pragma unroll
            for (int r = 0; r < 4; ++r)
                Kf[(((size_t)bb * H_ + h) * N_ + ns + r) * HD_ + hd] =
                    f2h(acc[1][mt][nt][r] + bk_);
            ushort4 o = {f2bf(acc[2][mt][nt][0] + bv_), f2bf(acc[2][mt][nt][1] + bv_),
                         f2bf(acc[2][mt][nt][2] + bv_), f2bf(acc[2][mt][nt][3] + bv_)};
            *(ushort4*)(Vt + (((size_t)bb * H_ + h) * HD_ + hd) * N_ + ns) = o;
        }
    }
}

// ---------------------------------------------------------------------------
// Flash attention, MFMA. v6: 8 waves x 32 q-rows (mt=2), QBLK=256.
// attn is LDS-BW-bound (R7 model: 160 b128-ops/block-kt ~= 38us floor at
// 128q/3blk); mt=2 reuses each K/V fragment for 2 MFMAs -> 96 b128-ops per
// 128-q equivalent (-40% LDS traffic), and halves barrier rendezvous per q.
// Cost: Ps 256x72 (36 KB), LDS 69 KB -> 2 blocks/CU (16 waves). Pipeline
// unchanged (prefetch-before-wait, counted vmcnt(2), 2 barriers/kt); per-wave
// body is R1-v2's verified mt=2 code. Grid 384 (bh x 4 q-tiles).
// ---------------------------------------------------------------------------
__global__ __launch_bounds__(512, 4) void attn_mfma(
    const u16* __restrict__ Qg, const u16* __restrict__ Kg,
    const u16* __restrict__ Vtg, u16* __restrict__ Og) {
    __shared__ __align__(16) u16 Ks[2][64 * 64];  // f16, rows permuted by g(rho)
    __shared__ __align__(16) u16 Vs[2][64 * 64];  // bf16 [hd][key], swizzled
    __shared__ __align__(16) u16 Ps[256 * 72];    // bf16 [q][key], wave-private rows

    const int t = threadIdx.x, lane = t & 63, w = t >> 6;   // w in 0..7
    const int quad = lane >> 4, ln = lane & 15;
    const int drow = lane >> 3, dcl = (lane & 7) ^ ((lane >> 3) & 7);
    const int id  = blockIdx.x;                  // 384
    const int id2 = (id & 7) * 48 + (id >> 3);   // XCD swizzle (384 % 8 == 0)
    const int bh  = id2 >> 2, qt = id2 & 3;
    const u16* Qh  = Qg  + ((size_t)bh * N_ + qt * 256) * HD_;
    const u16* Kh  = Kg  + (size_t)bh * N_ * HD_;
    const u16* Vth = Vtg + (size_t)bh * HD_ * N_;
    u16*       Oh  = Og  + ((size_t)bh * N_ + qt * 256) * HD_;

    const int rho = w * 8 + drow;                // 0..63: K-group / V-hd row
    const int gk  = 4 * (rho & 15) + (rho >> 4); // K row permutation

    f16x8 aq[2][2];
#pragma unroll
    for (int mt = 0; mt < 2; ++mt)
#pragma unroll
        for (int ks = 0; ks < 2; ++ks)
            aq[mt][ks] = *(const f16x8*)(Qh + (size_t)(w * 32 + mt * 16 + ln) * HD_ +
                                         ks * 32 + quad * 8);

    const bf16x8 pone = {0x3F80, 0x3F80, 0x3F80, 0x3F80,
                         0x3F80, 0x3F80, 0x3F80, 0x3F80};   // bf16 1.0 x8
    const f32x4 nb = {-EXPBIAS_, -EXPBIAS_, -EXPBIAS_, -EXPBIAS_};

    f32x4 oacc[2][4] = {};
    f32x4 lacc[2] = {};

    // prologue: stage kt=0 into buffer 0 (1 K-dma + 1 V-dma per thread;
    // 512 threads x 16B = 8 KB per tile)
    dma16(Kh + (size_t)gk * HD_ + dcl * 8, &Ks[0][w * 512]);
    dma16(Vth + (size_t)rho * N_ + dcl * 8, &Vs[0][w * 512]);

#pragma unroll 2
    for (int kt = 0; kt < 16; ++kt) {
        const int cur = kt & 1;
        // issue next tile's loads into the other buffer (last read at kt-1,
        // one full barrier behind -> safe), then wait only for the CURRENT
        // buffer's 2 loads: the 2 newer stay in flight across the barrier.
        if (kt < 15) {
            const int nk = (kt + 1) * 64;
            dma16(Kh + (size_t)(nk + gk) * HD_ + dcl * 8, &Ks[cur ^ 1][w * 512]);
            dma16(Vth + (size_t)rho * N_ + nk + dcl * 8, &Vs[cur ^ 1][w * 512]);
            asm volatile("s_waitcnt vmcnt(2)" ::: "memory");
        } else {
            asm volatile("s_waitcnt vmcnt(0)" ::: "memory");
        }
        __builtin_amdgcn_s_barrier();
        __builtin_amdgcn_sched_barrier(0);

        // S = Q K^T - 20*log2e (bias folded into C-init);
        // each K fragment (b0,b1) feeds BOTH mt MFMAs (register reuse).
        f32x4 sf[2][4];
        __builtin_amdgcn_s_setprio(1);
#pragma unroll
        for (int nt = 0; nt < 4; ++nt) {
            f16x8 b0 = *(const f16x8*)&Ks[cur][(nt * 16 + ln) * 64 + ((quad) ^ (ln & 7)) * 8];
            f16x8 b1 = *(const f16x8*)&Ks[cur][(nt * 16 + ln) * 64 + ((4 + quad) ^ (ln & 7)) * 8];
#pragma unroll
            for (int mt = 0; mt < 2; ++mt) {
                sf[mt][nt] = __builtin_amdgcn_mfma_f32_16x16x32_f16(aq[mt][0], b0, nb, 0, 0, 0);
                sf[mt][nt] = __builtin_amdgcn_mfma_f32_16x16x32_f16(aq[mt][1], b1, sf[mt][nt], 0, 0, 0);
            }
        }
        __builtin_amdgcn_s_setprio(0);

        // p = exp2(s'); pack 4 contiguous keys -> one b64 LDS write
#pragma unroll
        for (int mt = 0; mt < 2; ++mt)
#pragma unroll
            for (int r = 0; r < 4; ++r) {
                float e0 = EXP2F(sf[mt][0][r]);
                float e1 = EXP2F(sf[mt][1][r]);
                float e2 = EXP2F(sf[mt][2][r]);
                float e3 = EXP2F(sf[mt][3][r]);
                uint2 pk;
                pk.x = cvtpk_bf16(e0, e1);
                pk.y = cvtpk_bf16(e2, e3);
                int q = w * 32 + mt * 16 + quad * 4 + r;
                *(uint2*)&Ps[q * 72 + ln * 4] = pk;
            }

        // O += P V ; lsum += P x ones (row-sum of ROUNDED P on MFMA pipe).
        // Each V fragment (bv0,bv1) feeds BOTH mt MFMAs (register reuse).
        __builtin_amdgcn_s_setprio(1);
        {
            bf16x8 ap0[2], ap1[2];
#pragma unroll
            for (int mt = 0; mt < 2; ++mt) {
                ap0[mt] = *(const bf16x8*)&Ps[(w * 32 + mt * 16 + ln) * 72 + quad * 8];
                ap1[mt] = *(const bf16x8*)&Ps[(w * 32 + mt * 16 + ln) * 72 + 32 + quad * 8];
                lacc[mt] = __builtin_amdgcn_mfma_f32_16x16x32_bf16(ap0[mt], pone, lacc[mt], 0, 0, 0);
                lacc[mt] = __builtin_amdgcn_mfma_f32_16x16x32_bf16(ap1[mt], pone, lacc[mt], 0, 0, 0);
            }
#pragma unroll
            for (int nt = 0; nt < 4; ++nt) {
                bf16x8 bv0 = *(const bf16x8*)&Vs[cur][(nt * 16 + ln) * 64 +
                                                      ((quad ^ (ln & 7)) * 8)];
                bf16x8 bv1 = *(const bf16x8*)&Vs[cur][(nt * 16 + ln) * 64 +
                                                      (((4 + quad) ^ (ln & 7)) * 8)];
#pragma unroll
                for (int mt = 0; mt < 2; ++mt) {
                    oacc[mt][nt] = __builtin_amdgcn_mfma_f32_16x16x32_bf16(
                        ap0[mt], bv0, oacc[mt][nt], 0, 0, 0);
                    oacc[mt][nt] = __builtin_amdgcn_mfma_f32_16x16x32_bf16(
                        ap1[mt], bv1, oacc[mt][nt], 0, 0, 0);
                }
            }
        }
        __builtin_amdgcn_s_setprio(0);
        __builtin_amdgcn_sched_barrier(0);
        __builtin_amdgcn_s_barrier();   // all waves done reading buf[cur]
    }

    const float sc = 0.036084391824351615f;  // 1/sqrt(768), AFTER softmax
#pragma unroll
    for (int mt = 0; mt < 2; ++mt)
#pragma unroll
        for (int r = 0; r < 4; ++r) {
            float inv = sc / lacc[mt][r];    // lane's row q = w*32+mt*16+quad*4+r
#pragma unroll
            for (int nt = 0; nt < 4; ++nt)
                Oh[(size_t)(w * 32 + mt * 16 + quad * 4 + r) * HD_ + nt * 16 + ln] =
                    f2h(oacc[mt][nt][r] * inv);
        }
}

// ---------------------------------------------------------------------------
// Output projection: out = O @ Wo + bo. 128x64 single-buffer (R1-proven)
// + XCD swizzle. 768 = 3 blocks/CU.
// ---------------------------------------------------------------------------
__global__ __launch_bounds__(256) void gemm_out(
    const u16* __restrict__ Ob, const u16* __restrict__ Wto,
    const float* __restrict__ bias, float* __restrict__ Out) {
    __shared__ __align__(16) u16 As[128 * 64];
    __shared__ __align__(16) u16 Bs[64 * 64];

    const int id  = blockIdx.x;                  // 768
    const int id2 = (id & 7) * 96 + (id >> 3);
    const int m0  = (id2 / 12) * 128, n0 = (id2 % 12) * 64;

    const int t = threadIdx.x, lane = t & 63, w = t >> 6;
    const int wm = w >> 1, wn = w & 1;
    const int quad = lane >> 4, ln = lane & 15;
    const int drow = lane >> 3, dcl = (lane & 7) ^ ((lane >> 3) & 7);

    f32x4 acc[4][2] = {};
    for (int k0 = 0; k0 < D_; k0 += 64) {
        int head = k0 >> 6;
        __syncthreads();
#pragma unroll
        for (int j = 0; j < 4; ++j) {
            int i = w * 4 + j, row = i * 8 + drow;
            int m = m0 + row, bb = m >> 10, ns = m & 1023;
            dma16(Ob + (((size_t)bb * H_ + head) * N_ + ns) * HD_ + dcl * 8, &As[i * 512]);
        }
#pragma unroll
        for (int j = 0; j < 2; ++j) {
            int i = w * 2 + j, row = i * 8 + drow;
            dma16(Wto + (size_t)(n0 + row) * D_ + k0 + dcl * 8, &Bs[i * 512]);
        }
        __syncthreads();
        f16x8 a[4][2], b[2][2];
#pragma unroll
        for (int mt = 0; mt < 4; ++mt)
#pragma unroll
            for (int ks = 0; ks < 2; ++ks)
                a[mt][ks] = *(const f16x8*)&As[(wm * 64 + mt * 16 + ln) * 64 +
                                               (((ks * 4 + quad) ^ (ln & 7)) * 8)];
#pragma unroll
        for (int nt = 0; nt < 2; ++nt)
#pragma unroll
            for (int ks = 0; ks < 2; ++ks)
                b[nt][ks] = *(const f16x8*)&Bs[(wn * 32 + nt * 16 + ln) * 64 +
                                               (((ks * 4 + quad) ^ (ln & 7)) * 8)];
#pragma unroll
        for (int mt = 0; mt < 4; ++mt)
#pragma unroll
            for (int nt = 0; nt < 2; ++nt) {
                acc[mt][nt] = __builtin_amdgcn_mfma_f32_16x16x32_f16(
                    a[mt][0], b[nt][0], acc[mt][nt], 0, 0, 0);
                acc[mt][nt] = __builtin_amdgcn_mfma_f32_16x16x32_f16(
                    a[mt][1], b[nt][1], acc[mt][nt], 0, 0, 0);
            }
    }
#pragma unroll
    for (int nt = 0; nt < 2; ++nt) {
        int n = n0 + wn * 32 + nt * 16 + ln;
        float bv_ = bias[n];
#pragma unroll
        for (int mt = 0; mt < 4; ++mt) {
            int mb = m0 + wm * 64 + mt * 16 + quad * 4;
#pragma unroll
            for (int r = 0; r < 4; ++r)
                Out[(size_t)(mb + r) * D_ + n] = acc[mt][nt][r] + bv_;
        }
    }
}

extern "C" void kernel_launch(void* const* d_in, const int* in_sizes, int n_in,
                              void* d_out, int out_size, void* d_ws, size_t ws_size,
                              hipStream_t stream) {
    const float* x  = (const float*)d_in[0];
    const float* Wq = (const float*)d_in[1];
    const float* bq = (const float*)d_in[2];
    const float* Wk = (const float*)d_in[3];
    const float* bk = (const float*)d_in[4];
    const float* Wv = (const float*)d_in[5];
    const float* bv = (const float*)d_in[6];
    const float* Wo = (const float*)d_in[7];
    const float* bo = (const float*)d_in[8];

    u16* Xh = (u16*)d_ws;                  // x f16, 12.6 MB
    u16* Wt = Xh + XELEM;                  // 4 W^T f16
    u16* Qf = Wt + 4 * (size_t)WELEM;      // Q f16 (B,H,N,HD), pre-scaled by log2e
    u16* Kf = Qf + XELEM;                  // K f16 (B,H,N,HD)
    u16* Vt = Kf + XELEM;                  // V bf16 (B,H,HD,N)
    u16* Ob = Vt + XELEM;                  // attn out f16 (B,H,N,HD)

    cvt_x<<<dim3((int)(XELEM / 4 / 256)), 256, 0, stream>>>(x, Xh);
    cvt_w<<<dim3(144, 4), 256, 0, stream>>>(Wq, Wk, Wv, Wo, Wt);
    gemm_qkv<<<dim3(768), 256, 0, stream>>>(Xh, Wt, bq, bk, bv, Qf, Kf, Vt);
    attn_mfma<<<dim3(384), 512, 0, stream>>>(Qf, Kf, Vt, Ob);
    gemm_out<<<dim3(768), 256, 0, stream>>>(
        Ob, Wt + 3 * (size_t)WELEM, bo, (float*)d_out);
}

// Round 9
// 171.085 us; speedup vs baseline: 1.2453x; 1.0506x over previous
//
#include <hip/hip_runtime.h>

#define B_  8
#define N_  1024
#define D_  768
#define H_  12
#define HD_ 64
#define M_  (B_ * N_)            // 8192
#define WELEM (D_ * D_)          // 589824
#define XELEM ((size_t)M_ * D_)  // 6291456

typedef _Float16 f16;
typedef f16   f16x8  __attribute__((ext_vector_type(8)));
typedef short bf16x8 __attribute__((ext_vector_type(8)));
typedef float f32x4  __attribute__((ext_vector_type(4)));
typedef unsigned int u32x4 __attribute__((ext_vector_type(4)));
typedef unsigned short u16;

__device__ __forceinline__ u16 f2bf(float f) {
    unsigned int x = __float_as_uint(f);
    return (u16)((x + 0x7fffu + ((x >> 16) & 1u)) >> 16);   // RNE
}
__device__ __forceinline__ u16 f2h(float f) {
    return __builtin_bit_cast(u16, (f16)f);                 // RNE
}
// packed f32x2 -> bf16x2 in one VALU op
__device__ __forceinline__ unsigned int cvtpk_bf16(float lo, float hi) {
    unsigned int r;
    asm("v_cvt_pk_bf16_f32 %0, %1, %2" : "=v"(r) : "v"(lo), "v"(hi));
    return r;
}
#if __has_builtin(__builtin_amdgcn_exp2f)
#define EXP2F(x) __builtin_amdgcn_exp2f(x)
#else
#define EXP2F(x) exp2f(x)
#endif

#define LOG2E_   1.4426950408889634f
#define EXPBIAS_ 28.853900817779268f   // 20 * log2(e)

// direct global->LDS DMA, 16B per lane; dst = wave-uniform base + lane*16
typedef __attribute__((address_space(3))) unsigned int       as3_u32;
typedef __attribute__((address_space(1))) const unsigned int as1_u32;
__device__ __forceinline__ void dma16(const void* g, void* l) {
    __builtin_amdgcn_global_load_lds((as1_u32*)g, (as3_u32*)l, 16, 0, 0);
}

// ---------------------------------------------------------------------------
// x (fp32, M x D) -> f16, same layout.
// ---------------------------------------------------------------------------
__global__ __launch_bounds__(256) void cvt_x(const float* __restrict__ X,
                                             u16* __restrict__ Xh) {
    int idx = blockIdx.x * 256 + threadIdx.x;
    float4 v = ((const float4*)X)[idx];
    ushort4 o = {f2h(v.x), f2h(v.y), f2h(v.z), f2h(v.w)};
    ((ushort4*)Xh)[idx] = o;
}

// ---------------------------------------------------------------------------
// W (fp32, [k][n]) -> Wt (f16, [n][k]) for all 4 weights. 64x64 tiles.
// ---------------------------------------------------------------------------
__global__ __launch_bounds__(256) void cvt_w(
    const float* __restrict__ w0, const float* __restrict__ w1,
    const float* __restrict__ w2, const float* __restrict__ w3,
    u16* __restrict__ Wt) {
    const float* W = blockIdx.y == 0 ? w0 : blockIdx.y == 1 ? w1
                   : blockIdx.y == 2 ? w2 : w3;
    u16* dst = Wt + (size_t)blockIdx.y * WELEM;
    const int t  = threadIdx.x;
    const int tk = (blockIdx.x % 12) * 64, tn = (blockIdx.x / 12) * 64;
    __shared__ __align__(16) float tile[64][68];
#pragma unroll
    for (int i = 0; i < 4; ++i) {
        int r = (t >> 4) + i * 16, c4 = (t & 15) * 4;
        float4 v = *(const float4*)(W + (size_t)(tk + r) * D_ + tn + c4);
        *(float4*)&tile[r][c4] = v;
    }
    __syncthreads();
#pragma unroll
    for (int i = 0; i < 4; ++i) {
        int nr = (t >> 4) + i * 16, kc = (t & 15) * 4;
        ushort4 o = {f2h(tile[kc + 0][nr]), f2h(tile[kc + 1][nr]),
                     f2h(tile[kc + 2][nr]), f2h(tile[kc + 3][nr])};
        *(ushort4*)(dst + (size_t)(tn + nr) * D_ + tk + kc) = o;
    }
}

// ---------------------------------------------------------------------------
// QKV projection, Z-FUSED (R6-proven): one block computes Q, K and V 128x64
// tiles for its (m0,n0) -- As staged ONCE per K-step, reused for 3 W tiles.
// Single-buffer, 768 blocks = 3/CU, LDS 40 KB, XCD swizzle.
// Q output pre-scaled by log2(e).
// ---------------------------------------------------------------------------
__global__ __launch_bounds__(256, 3) void gemm_qkv(
    const u16* __restrict__ Xh, const u16* __restrict__ Wt,
    const float* __restrict__ bq, const float* __restrict__ bk,
    const float* __restrict__ bv, u16* __restrict__ Qf,
    u16* __restrict__ Kf, u16* __restrict__ Vt) {
    __shared__ __align__(16) u16 As[128 * 64];      // 16 KB
    __shared__ __align__(16) u16 Bs[3 * 64 * 64];   // 24 KB (Wq|Wk|Wv tiles)

    const int id  = blockIdx.x;                  // 768
    const int xcd = id & 7, idx = id >> 3;       // 96 per XCD
    const int m0  = (xcd * 8 + idx / 12) * 128;  // XCD owns 8 m-panels
    const int n0  = (idx % 12) * 64;

    const int t = threadIdx.x, lane = t & 63, w = t >> 6;
    const int wm = w >> 1, wn = w & 1;
    const int quad = lane >> 4, ln = lane & 15;
    const int drow = lane >> 3, dcl = (lane & 7) ^ ((lane >> 3) & 7);

    f32x4 acc[3][4][2] = {};
    for (int k0 = 0; k0 < D_; k0 += 64) {
        __syncthreads();
#pragma unroll
        for (int j = 0; j < 4; ++j) {
            int i = w * 4 + j, row = i * 8 + drow;
            dma16(Xh + (size_t)(m0 + row) * D_ + k0 + dcl * 8, &As[i * 512]);
        }
#pragma unroll
        for (int z = 0; z < 3; ++z)
#pragma unroll
            for (int j = 0; j < 2; ++j) {
                int i = w * 2 + j, row = i * 8 + drow;
                dma16(Wt + (size_t)z * WELEM + (size_t)(n0 + row) * D_ + k0 + dcl * 8,
                      &Bs[z * 4096 + i * 512]);
            }
        __syncthreads();
        f16x8 a[4][2];
#pragma unroll
        for (int mt = 0; mt < 4; ++mt)
#pragma unroll
            for (int ks = 0; ks < 2; ++ks)
                a[mt][ks] = *(const f16x8*)&As[(wm * 64 + mt * 16 + ln) * 64 +
                                               (((ks * 4 + quad) ^ (ln & 7)) * 8)];
#pragma unroll
        for (int z = 0; z < 3; ++z) {
            f16x8 b[2][2];
#pragma unroll
            for (int nt = 0; nt < 2; ++nt)
#pragma unroll
                for (int ks = 0; ks < 2; ++ks)
                    b[nt][ks] = *(const f16x8*)&Bs[z * 4096 +
                                                   (wn * 32 + nt * 16 + ln) * 64 +
                                                   (((ks * 4 + quad) ^ (ln & 7)) * 8)];
#pragma unroll
            for (int mt = 0; mt < 4; ++mt)
#pragma unroll
                for (int nt = 0; nt < 2; ++nt) {
                    acc[z][mt][nt] = __builtin_amdgcn_mfma_f32_16x16x32_f16(
                        a[mt][0], b[nt][0], acc[z][mt][nt], 0, 0, 0);
                    acc[z][mt][nt] = __builtin_amdgcn_mfma_f32_16x16x32_f16(
                        a[mt][1], b[nt][1], acc[z][mt][nt], 0, 0, 0);
                }
        }
    }
    const int h = n0 >> 6;
#pragma unroll
    for (int nt = 0; nt < 2; ++nt) {
        int hd = wn * 32 + nt * 16 + ln;
        float bq_ = bq[n0 + hd], bk_ = bk[n0 + hd], bv_ = bv[n0 + hd];
#pragma unroll
        for (int mt = 0; mt < 4; ++mt) {
            int mb = m0 + wm * 64 + mt * 16 + quad * 4;
            int bb = mb >> 10, ns = mb & 1023;
#pragma unroll
            for (int r = 0; r < 4; ++r)
                Qf[(((size_t)bb * H_ + h) * N_ + ns + r) * HD_ + hd] =
                    f2h((acc[0][mt][nt][r] + bq_) * LOG2E_);
#pragma unroll
            for (int r = 0; r < 4; ++r)
                Kf[(((size_t)bb * H_ + h) * N_ + ns + r) * HD_ + hd] =
                    f2h(acc[1][mt][nt][r] + bk_);
            ushort4 o = {f2bf(acc[2][mt][nt][0] + bv_), f2bf(acc[2][mt][nt][1] + bv_),
                         f2bf(acc[2][mt][nt][2] + bv_), f2bf(acc[2][mt][nt][3] + bv_)};
            *(ushort4*)(Vt + (((size_t)bb * H_ + h) * HD_ + hd) * N_ + ns) = o;
        }
    }
}

// ---------------------------------------------------------------------------
// Flash attention, MFMA. v7: SWAPPED-operand form (T12) -- P never touches
// LDS. S^T = mfma(A=K, B=Q): lane holds S[k=quad*4+r][q=ln]. With K-tile
// rows staged in permutation key(nt,m) = 32*(nt>>1) + (nt&1)*4 + (m>>2)*8
// + (m&3), the PV B-operand P^T (col=q=ln, k=quad*8+j) assembles LANE-
// LOCALLY from nt-even (j=0..3) and nt-odd (j=4..7) via 8 cvt_pk. PV is
// also swapped: O^T = mfma(A=V^T, B=P^T) -- Vs [hd][key] is already the
// A layout. lsum = mfma(ones, P^T) lands at col=q. O-writes become ushort4.
// LDS traffic: 24 -> 16 b128 per wave-kt per 32 q (-33%); Ps (36 KB) gone:
// LDS 32 KB. 4 waves x 32 q (2 groups), QBLK=128, grid 768 = 3 blocks/CU.
// Pipeline unchanged: prefetch-before-wait, counted vmcnt(4), 2 barriers/kt.
// ---------------------------------------------------------------------------
__global__ __launch_bounds__(256, 3) void attn_mfma(
    const u16* __restrict__ Qg, const u16* __restrict__ Kg,
    const u16* __restrict__ Vtg, u16* __restrict__ Og) {
    __shared__ __align__(16) u16 Ks[2][64 * 64];  // f16 [key(perm)][d], d-swizzled
    __shared__ __align__(16) u16 Vs[2][64 * 64];  // bf16 [hd][key], key-swizzled

    const int t = threadIdx.x, lane = t & 63, w = t >> 6;   // w in 0..3
    const int quad = lane >> 4, ln = lane & 15;
    const int drow = lane >> 3, dcl = (lane & 7) ^ ((lane >> 3) & 7);
    const int id  = blockIdx.x;                  // 768
    const int id2 = (id & 7) * 96 + (id >> 3);
    const int bh  = id2 >> 3, qt = id2 & 7;
    const u16* Qh  = Qg  + ((size_t)bh * N_ + qt * 128) * HD_;
    const u16* Kh  = Kg  + (size_t)bh * N_ * HD_;
    const u16* Vth = Vtg + (size_t)bh * HD_ * N_;
    u16*       Oh  = Og  + ((size_t)bh * N_ + qt * 128) * HD_;

    // staging rows: this thread fills LDS rows rho0, rho1 (j=0,1)
    const int rho0 = w * 16 + drow, rho1 = rho0 + 8;
    // K row permutation: LDS row rho holds global key gmap(rho)
    const int gm0 = 32 * (rho0 >> 5) + ((rho0 >> 4) & 1) * 4 +
                    ((rho0 >> 2) & 3) * 8 + (rho0 & 3);
    const int gm1 = 32 * (rho1 >> 5) + ((rho1 >> 4) & 1) * 4 +
                    ((rho1 >> 2) & 3) * 8 + (rho1 & 3);

    // Q as B-operand: col=q=ln per group g, k-elem = d = ks*32 + quad*8 + j
    f16x8 aq[2][2];
#pragma unroll
    for (int g = 0; g < 2; ++g)
#pragma unroll
        for (int ks = 0; ks < 2; ++ks)
            aq[g][ks] = *(const f16x8*)(Qh + (size_t)(w * 32 + g * 16 + ln) * HD_ +
                                        ks * 32 + quad * 8);

    const bf16x8 pone = {0x3F80, 0x3F80, 0x3F80, 0x3F80,
                         0x3F80, 0x3F80, 0x3F80, 0x3F80};   // bf16 1.0 x8
    const f32x4 nb = {-EXPBIAS_, -EXPBIAS_, -EXPBIAS_, -EXPBIAS_};

    f32x4 oacc[2][4] = {};
    f32x4 lacc[2] = {};

    // prologue: stage kt=0 into buffer 0 (2 K-dma + 2 V-dma per thread)
    dma16(Kh + (size_t)gm0 * HD_ + dcl * 8, &Ks[0][(w * 2 + 0) * 512]);
    dma16(Kh + (size_t)gm1 * HD_ + dcl * 8, &Ks[0][(w * 2 + 1) * 512]);
    dma16(Vth + (size_t)rho0 * N_ + dcl * 8, &Vs[0][(w * 2 + 0) * 512]);
    dma16(Vth + (size_t)rho1 * N_ + dcl * 8, &Vs[0][(w * 2 + 1) * 512]);

#pragma unroll 2
    for (int kt = 0; kt < 16; ++kt) {
        const int cur = kt & 1;
        // issue next tile's loads into the other buffer (last read at kt-1,
        // one full barrier behind -> safe), then wait only for the CURRENT
        // buffer's 4 loads: the 4 newer stay in flight across the barrier.
        if (kt < 15) {
            const int nk = (kt + 1) * 64;
            dma16(Kh + (size_t)(nk + gm0) * HD_ + dcl * 8, &Ks[cur ^ 1][(w * 2 + 0) * 512]);
            dma16(Kh + (size_t)(nk + gm1) * HD_ + dcl * 8, &Ks[cur ^ 1][(w * 2 + 1) * 512]);
            dma16(Vth + (size_t)rho0 * N_ + nk + dcl * 8, &Vs[cur ^ 1][(w * 2 + 0) * 512]);
            dma16(Vth + (size_t)rho1 * N_ + nk + dcl * 8, &Vs[cur ^ 1][(w * 2 + 1) * 512]);
            asm volatile("s_waitcnt vmcnt(4)" ::: "memory");
        } else {
            asm volatile("s_waitcnt vmcnt(0)" ::: "memory");
        }
        __builtin_amdgcn_s_barrier();
        __builtin_amdgcn_sched_barrier(0);

        // S^T = K Q^T - bias: A=K fragment (LDS), B=Q (regs). Each K fragment
        // feeds BOTH q-groups. Output: S[key=gmap(nt,quad*4+r)][q=ln].
        f32x4 sf[2][4];
        __builtin_amdgcn_s_setprio(1);
#pragma unroll
        for (int nt = 0; nt < 4; ++nt) {
            f16x8 k0 = *(const f16x8*)&Ks[cur][(nt * 16 + ln) * 64 + ((quad) ^ (ln & 7)) * 8];
            f16x8 k1 = *(const f16x8*)&Ks[cur][(nt * 16 + ln) * 64 + ((4 + quad) ^ (ln & 7)) * 8];
#pragma unroll
            for (int g = 0; g < 2; ++g) {
                sf[g][nt] = __builtin_amdgcn_mfma_f32_16x16x32_f16(k0, aq[g][0], nb, 0, 0, 0);
                sf[g][nt] = __builtin_amdgcn_mfma_f32_16x16x32_f16(k1, aq[g][1], sf[g][nt], 0, 0, 0);
            }
        }
        __builtin_amdgcn_s_setprio(0);

        // p = exp2(s'); assemble PV B-operand P^T lane-locally:
        // chunk c keys c*32+quad*8+{0..7} = nt=2c (j=0..3) + nt=2c+1 (j=4..7)
        bf16x8 pb[2][2];
#pragma unroll
        for (int g = 0; g < 2; ++g)
#pragma unroll
            for (int c = 0; c < 2; ++c) {
                unsigned int p0 = cvtpk_bf16(EXP2F(sf[g][2 * c][0]), EXP2F(sf[g][2 * c][1]));
                unsigned int p1 = cvtpk_bf16(EXP2F(sf[g][2 * c][2]), EXP2F(sf[g][2 * c][3]));
                unsigned int p2 = cvtpk_bf16(EXP2F(sf[g][2 * c + 1][0]), EXP2F(sf[g][2 * c + 1][1]));
                unsigned int p3 = cvtpk_bf16(EXP2F(sf[g][2 * c + 1][2]), EXP2F(sf[g][2 * c + 1][3]));
                u32x4 pk = {p0, p1, p2, p3};
                pb[g][c] = __builtin_bit_cast(bf16x8, pk);
            }

        // O^T += V^T P^T (A=V from LDS, B=P^T regs); lsum = ones x P^T.
        // Each V fragment feeds BOTH q-groups.
        __builtin_amdgcn_s_setprio(1);
#pragma unroll
        for (int g = 0; g < 2; ++g) {
            lacc[g] = __builtin_amdgcn_mfma_f32_16x16x32_bf16(pone, pb[g][0], lacc[g], 0, 0, 0);
            lacc[g] = __builtin_amdgcn_mfma_f32_16x16x32_bf16(pone, pb[g][1], lacc[g], 0, 0, 0);
        }
#pragma unroll
        for (int nt = 0; nt < 4; ++nt) {
            bf16x8 v0 = *(const bf16x8*)&Vs[cur][(nt * 16 + ln) * 64 +
                                                 ((quad ^ (ln & 7)) * 8)];
            bf16x8 v1 = *(const bf16x8*)&Vs[cur][(nt * 16 + ln) * 64 +
                                                 (((4 + quad) ^ (ln & 7)) * 8)];
#pragma unroll
            for (int g = 0; g < 2; ++g) {
                oacc[g][nt] = __builtin_amdgcn_mfma_f32_16x16x32_bf16(
                    v0, pb[g][0], oacc[g][nt], 0, 0, 0);
                oacc[g][nt] = __builtin_amdgcn_mfma_f32_16x16x32_bf16(
                    v1, pb[g][1], oacc[g][nt], 0, 0, 0);
            }
        }
        __builtin_amdgcn_s_setprio(0);
        __builtin_amdgcn_sched_barrier(0);
        __builtin_amdgcn_s_barrier();   // all waves done reading buf[cur]
    }

    // O^T: lane holds O[q = w*32+g*16+ln][hd = nt*16 + quad*4 + r], r=0..3
    // contiguous -> ushort4 writes. lacc[g] cols = q (all 4 regs equal).
    const float sc = 0.036084391824351615f;  // 1/sqrt(768), AFTER softmax
#pragma unroll
    for (int g = 0; g < 2; ++g) {
        float inv = sc / lacc[g][0];
        u16* orow = Oh + (size_t)(w * 32 + g * 16 + ln) * HD_ + quad * 4;
#pragma unroll
        for (int nt = 0; nt < 4; ++nt) {
            ushort4 o = {f2h(oacc[g][nt][0] * inv), f2h(oacc[g][nt][1] * inv),
                         f2h(oacc[g][nt][2] * inv), f2h(oacc[g][nt][3] * inv)};
            *(ushort4*)(orow + nt * 16) = o;
        }
    }
}

// ---------------------------------------------------------------------------
// Output projection: out = O @ Wo + bo. 128x64 single-buffer (R1-proven)
// + XCD swizzle. 768 = 3 blocks/CU.
// ---------------------------------------------------------------------------
__global__ __launch_bounds__(256) void gemm_out(
    const u16* __restrict__ Ob, const u16* __restrict__ Wto,
    const float* __restrict__ bias, float* __restrict__ Out) {
    __shared__ __align__(16) u16 As[128 * 64];
    __shared__ __align__(16) u16 Bs[64 * 64];

    const int id  = blockIdx.x;                  // 768
    const int id2 = (id & 7) * 96 + (id >> 3);
    const int m0  = (id2 / 12) * 128, n0 = (id2 % 12) * 64;

    const int t = threadIdx.x, lane = t & 63, w = t >> 6;
    const int wm = w >> 1, wn = w & 1;
    const int quad = lane >> 4, ln = lane & 15;
    const int drow = lane >> 3, dcl = (lane & 7) ^ ((lane >> 3) & 7);

    f32x4 acc[4][2] = {};
    for (int k0 = 0; k0 < D_; k0 += 64) {
        int head = k0 >> 6;
        __syncthreads();
#pragma unroll
        for (int j = 0; j < 4; ++j) {
            int i = w * 4 + j, row = i * 8 + drow;
            int m = m0 + row, bb = m >> 10, ns = m & 1023;
            dma16(Ob + (((size_t)bb * H_ + head) * N_ + ns) * HD_ + dcl * 8, &As[i * 512]);
        }
#pragma unroll
        for (int j = 0; j < 2; ++j) {
            int i = w * 2 + j, row = i * 8 + drow;
            dma16(Wto + (size_t)(n0 + row) * D_ + k0 + dcl * 8, &Bs[i * 512]);
        }
        __syncthreads();
        f16x8 a[4][2], b[2][2];
#pragma unroll
        for (int mt = 0; mt < 4; ++mt)
#pragma unroll
            for (int ks = 0; ks < 2; ++ks)
                a[mt][ks] = *(const f16x8*)&As[(wm * 64 + mt * 16 + ln) * 64 +
                                               (((ks * 4 + quad) ^ (ln & 7)) * 8)];
#pragma unroll
        for (int nt = 0; nt < 2; ++nt)
#pragma unroll
            for (int ks = 0; ks < 2; ++ks)
                b[nt][ks] = *(const f16x8*)&Bs[(wn * 32 + nt * 16 + ln) * 64 +
                                               (((ks * 4 + quad) ^ (ln & 7)) * 8)];
#pragma unroll
        for (int mt = 0; mt < 4; ++mt)
#pragma unroll
            for (int nt = 0; nt < 2; ++nt) {
                acc[mt][nt] = __builtin_amdgcn_mfma_f32_16x16x32_f16(
                    a[mt][0], b[nt][0], acc[mt][nt], 0, 0, 0);
                acc[mt][nt] = __builtin_amdgcn_mfma_f32_16x16x32_f16(
                    a[mt][1], b[nt][1], acc[mt][nt], 0, 0, 0);
            }
    }
#pragma unroll
    for (int nt = 0; nt < 2; ++nt) {
        int n = n0 + wn * 32 + nt * 16 + ln;
        float bv_ = bias[n];
#pragma unroll
        for (int mt = 0; mt < 4; ++mt) {
            int mb = m0 + wm * 64 + mt * 16 + quad * 4;
#pragma unroll
            for (int r = 0; r < 4; ++r)
                Out[(size_t)(mb + r) * D_ + n] = acc[mt][nt][r] + bv_;
        }
    }
}

extern "C" void kernel_launch(void* const* d_in, const int* in_sizes, int n_in,
                              void* d_out, int out_size, void* d_ws, size_t ws_size,
                              hipStream_t stream) {
    const float* x  = (const float*)d_in[0];
    const float* Wq = (const float*)d_in[1];
    const float* bq = (const float*)d_in[2];
    const float* Wk = (const float*)d_in[3];
    const float* bk = (const float*)d_in[4];
    const float* Wv = (const float*)d_in[5];
    const float* bv = (const float*)d_in[6];
    const float* Wo = (const float*)d_in[7];
    const float* bo = (const float*)d_in[8];

    u16* Xh = (u16*)d_ws;                  // x f16, 12.6 MB
    u16* Wt = Xh + XELEM;                  // 4 W^T f16
    u16* Qf = Wt + 4 * (size_t)WELEM;      // Q f16 (B,H,N,HD), pre-scaled by log2e
    u16* Kf = Qf + XELEM;                  // K f16 (B,H,N,HD)
    u16* Vt = Kf + XELEM;                  // V bf16 (B,H,HD,N)
    u16* Ob = Vt + XELEM;                  // attn out f16 (B,H,N,HD)

    cvt_x<<<dim3((int)(XELEM / 4 / 256)), 256, 0, stream>>>(x, Xh);
    cvt_w<<<dim3(144, 4), 256, 0, stream>>>(Wq, Wk, Wv, Wo, Wt);
    gemm_qkv<<<dim3(768), 256, 0, stream>>>(Xh, Wt, bq, bk, bv, Qf, Kf, Vt);
    attn_mfma<<<dim3(768), 256, 0, stream>>>(Qf, Kf, Vt, Ob);
    gemm_out<<<dim3(768), 256, 0, stream>>>(
        Ob, Wt + 3 * (size_t)WELEM, bo, (float*)d_out);
}